// Round 10
// baseline (936.279 us; speedup 1.0000x reference)
//
#include <hip/hip_runtime.h>
#include <hip/hip_bf16.h>

typedef _Float16 f16;
typedef _Float16 half8 __attribute__((ext_vector_type(8)));
typedef float f32x4 __attribute__((ext_vector_type(4)));
typedef float f32x16 __attribute__((ext_vector_type(16)));

#define S_LEN 1024
#define DMODEL 512
#define NFFT   2048
#define RPB    2048     // rows per batch: f=1..1023 pairs + packed (DC.re, Nyq.re) in rows 0,1
#define RTOT   4096     // 2 batches -> exactly 32 row-tiles of 128
#define CPS    1064     // cpcm f-stride
#define NROW   2048     // B*S
#define NPART  8        // split-K partials for spectral GEMM

__device__ __forceinline__ float2 mkf2(float a, float b) { float2 r; r.x = a; r.y = b; return r; }
__device__ __forceinline__ int zp(int i) { return i + (i >> 5); }   // LDS bank-pad for FFT array

// async global->LDS (16B per lane). LDS dest must be wave-uniform base; lane writes at +lane*16.
__device__ __forceinline__ void gl16(const f16* g, f16* l) {
  __builtin_amdgcn_global_load_lds((const __attribute__((address_space(1))) void*)g,
                                   (__attribute__((address_space(3))) void*)l, 16, 0, 0);
}

// ---------------- FFT-2048 in LDS: fused radix-2^2, padded indexing ----------------
template<bool INV>
__device__ __forceinline__ void fft2048(float2* z, const float2* __restrict__ tw, int tid) {
  for (int i = tid; i < 2048; i += 256) {
    int j = (int)(__brev((unsigned)i) >> 21);
    if (i < j) { float2 a = z[zp(i)]; z[zp(i)] = z[zp(j)]; z[zp(j)] = a; }
  }
  __syncthreads();
#pragma unroll
  for (int sl = 1; sl <= 9; sl += 2) {    // fused stages (sl, sl+1)
    const int h = 1 << (sl - 1);
    for (int q = tid; q < 512; q += 256) {
      int j = q & (h - 1);
      int base = (q >> (sl - 1)) << (sl + 1);
      int i0 = base + j;
      float2 a0 = z[zp(i0)], a1 = z[zp(i0 + h)], a2 = z[zp(i0 + 2 * h)], a3 = z[zp(i0 + 3 * h)];
      float2 w1 = tw[j << (11 - sl)];
      float2 w2 = tw[j << (10 - sl)];
      float2 w3 = tw[(j + h) << (10 - sl)];
      if (INV) { w1.y = -w1.y; w2.y = -w2.y; w3.y = -w3.y; }
      float tr, ti;
      tr = a1.x * w1.x - a1.y * w1.y; ti = a1.x * w1.y + a1.y * w1.x;
      float2 b0 = mkf2(a0.x + tr, a0.y + ti), b1 = mkf2(a0.x - tr, a0.y - ti);
      tr = a3.x * w1.x - a3.y * w1.y; ti = a3.x * w1.y + a3.y * w1.x;
      float2 b2 = mkf2(a2.x + tr, a2.y + ti), b3 = mkf2(a2.x - tr, a2.y - ti);
      tr = b2.x * w2.x - b2.y * w2.y; ti = b2.x * w2.y + b2.y * w2.x;
      z[zp(i0)]         = mkf2(b0.x + tr, b0.y + ti);
      z[zp(i0 + 2 * h)] = mkf2(b0.x - tr, b0.y - ti);
      tr = b3.x * w3.x - b3.y * w3.y; ti = b3.x * w3.y + b3.y * w3.x;
      z[zp(i0 + h)]     = mkf2(b1.x + tr, b1.y + ti);
      z[zp(i0 + 3 * h)] = mkf2(b1.x - tr, b1.y - ti);
    }
    __syncthreads();
  }
  for (int j = tid; j < 1024; j += 256) {  // final radix-2 stage
    float2 w = tw[j];
    if (INV) w.y = -w.y;
    float2 a = z[zp(j)], b = z[zp(j + 1024)];
    float tr = b.x * w.x - b.y * w.y, ti = b.x * w.y + b.y * w.x;
    z[zp(j)]        = mkf2(a.x + tr, a.y + ti);
    z[zp(j + 1024)] = mkf2(a.x - tr, a.y - ti);
  }
  __syncthreads();
}

// ---------------- init kernels ----------------
__global__ void k_twiddle(float2* tw) {
  int i = blockIdx.x * 256 + threadIdx.x;
  if (i < 1024) {
    float ang = -6.2831853071795864769f * (float)i / 2048.0f;
    tw[i] = mkf2(cosf(ang), sinf(ang));
  }
}

// rfft of phi columns (pairs packed into one complex FFT)
__global__ void k_fft_phi(const float* __restrict__ phi, float2* __restrict__ Vf,
                          const float2* __restrict__ tw) {
  __shared__ float2 z[2112];
  int tid = threadIdx.x;
  int k0 = blockIdx.x * 2;
  for (int t = tid; t < 1024; t += 256)
    z[zp(t)] = *(const float2*)(phi + (size_t)t * 16 + k0);
  for (int t = 1024 + tid; t < 2048; t += 256) z[zp(t)] = mkf2(0.f, 0.f);
  __syncthreads();
  fft2048<false>(z, tw, tid);
  for (int f = tid; f <= 1024; f += 256) {
    float2 zf = z[zp(f)], zc = z[zp((2048 - f) & 2047)];
    Vf[(size_t)k0 * 1025 + f]       = mkf2(0.5f * (zf.x + zc.x), 0.5f * (zf.y - zc.y));
    Vf[(size_t)(k0 + 1) * 1025 + f] = mkf2(0.5f * (zf.y + zc.y), 0.5f * (zc.x - zf.x));
  }
}

// cpcm[kb][f]: f=1..1023 standard complex scale; slot 0 packs (c_DC, c_Nyq) (both REAL).
__global__ void k_cpcm(const float2* __restrict__ Vf, const float* __restrict__ sigma,
                       float2* __restrict__ cpcm) {
  int idx = blockIdx.x * 256 + threadIdx.x;
  if (idx >= 32 * CPS) return;
  int kb = idx / CPS, f = idx - kb * CPS;
  int k = kb & 15;
  float s = powf(sigma[k], 0.25f) * (1.0f / 2048.0f);
  float2 v = mkf2(0.f, 0.f);
  if (f == 0) {
    float dc = Vf[(size_t)k * 1025].x;          // real
    float ny = Vf[(size_t)k * 1025 + 1024].x;   // real
    v = (kb < 16) ? mkf2(s * dc, s * ny) : mkf2(s * ny, s * dc);
  } else if (f <= 1023) {
    if (kb < 16) {
      v = Vf[(size_t)k * 1025 + f];
    } else {
      float2 t = Vf[(size_t)k * 1025 + (1024 - f)];
      v = mkf2(t.x, -t.y);
    }
    v.x *= s; v.y *= s;
  }
  cpcm[idx] = v;
}

// ---------------- per-layer weight cast/transpose ----------------
__global__ void k_cast(const float* __restrict__ mp, const float* __restrict__ mm,
                       const float* __restrict__ mu, const float* __restrict__ fc1,
                       const float* __restrict__ fc2,
                       f16* __restrict__ Wsp, f16* __restrict__ Wu,
                       f16* __restrict__ Wf1, f16* __restrict__ Wf2) {
  __shared__ float T[64][65];
  int blk = blockIdx.x, tid = threadIdx.x;
  if (blk < 2048) {                    // Wsp: Wsp[(kb*512+o)][d] = m?[k][d][o]
    int mat = blk >> 6, tile = blk & 63;
    int d0 = (tile >> 3) * 64, o0 = (tile & 7) * 64;
    const float* src = (mat < 16) ? (mp + (size_t)mat * 262144)
                                  : (mm + (size_t)(mat - 16) * 262144);
    for (int q = tid; q < 4096; q += 256) {
      int i = q >> 6, j = q & 63;
      T[i][j] = src[(size_t)(d0 + i) * 512 + o0 + j];
    }
    __syncthreads();
    for (int q = tid; q < 4096; q += 256) {
      int i = q >> 6, j = q & 63;
      Wsp[(size_t)(mat * 512 + o0 + i) * 512 + d0 + j] = (f16)T[j][i];
    }
  } else if (blk < 2240) {             // Wu: Wu[o][ip*512+d] = mu[2-ip][d][o]
    int q0 = blk - 2048;
    int ip = q0 >> 6, tile = q0 & 63;
    int d0 = (tile >> 3) * 64, o0 = (tile & 7) * 64;
    const float* src = mu + (size_t)(2 - ip) * 262144;
    for (int q = tid; q < 4096; q += 256) {
      int i = q >> 6, j = q & 63;
      T[i][j] = src[(size_t)(d0 + i) * 512 + o0 + j];
    }
    __syncthreads();
    for (int q = tid; q < 4096; q += 256) {
      int i = q >> 6, j = q & 63;
      Wu[(size_t)(o0 + i) * 1536 + ip * 512 + d0 + j] = (f16)T[j][i];
    }
  } else if (blk < 3264) {             // fc1 perm copy: row 2h = y-row h, 2h+1 = gate-row h
    int q0 = blk - 2240;
    size_t e = ((size_t)q0 * 256 + tid) * 8;
    int jj = (int)(e >> 9), col = (int)(e & 511);
    int srow = (jj & 1) ? (2048 + (jj >> 1)) : (jj >> 1);
    const float4* s = (const float4*)(fc1 + (size_t)srow * 512 + col);
    float4 a = s[0], b = s[1];
    union { f16 h[8]; uint4 u; } pk;
    pk.h[0] = (f16)a.x; pk.h[1] = (f16)a.y; pk.h[2] = (f16)a.z; pk.h[3] = (f16)a.w;
    pk.h[4] = (f16)b.x; pk.h[5] = (f16)b.y; pk.h[6] = (f16)b.z; pk.h[7] = (f16)b.w;
    *(uint4*)(Wf1 + (size_t)jj * 512 + col) = pk.u;
  } else {                             // fc2 straight copy (already [o][j])
    int q0 = blk - 3264;
    size_t e = ((size_t)q0 * 256 + tid) * 8;
    const float4* s = (const float4*)(fc2 + e);
    float4 a = s[0], b = s[1];
    union { f16 h[8]; uint4 u; } pk;
    pk.h[0] = (f16)a.x; pk.h[1] = (f16)a.y; pk.h[2] = (f16)a.z; pk.h[3] = (f16)a.w;
    pk.h[4] = (f16)b.x; pk.h[5] = (f16)b.y; pk.h[6] = (f16)b.z; pk.h[7] = (f16)b.w;
    *(uint4*)(Wf2 + e) = pk.u;
  }
}

// ---------------- rmsnorm (f16 x in, zero-padded fp16 hb2 out) ----------------
__global__ void k_rmsnorm(const f16* __restrict__ x, const float* __restrict__ w,
                          f16* __restrict__ hb2) {
  int tid = threadIdx.x, l = tid & 63, wv = tid >> 6;
  int r = blockIdx.x * 4 + wv;
  int b = r >> 10, t = r & 1023;
  const f16* xr = x + (size_t)r * 512;
  f16* hr = hb2 + (size_t)(b * 1026 + 2 + t) * 512;
  float v[8]; float ss = 0.f;
#pragma unroll
  for (int j = 0; j < 8; ++j) { v[j] = (float)xr[j * 64 + l]; ss += v[j] * v[j]; }
#pragma unroll
  for (int o = 32; o; o >>= 1) ss += __shfl_xor(ss, o, 64);
  float rn = rsqrtf(ss * (1.f / 512.f) + 1e-5f);
#pragma unroll
  for (int j = 0; j < 8; ++j) {
    float hv = v[j] * rn * w[j * 64 + l];
    hr[j * 64 + l] = (f16)hv;
  }
}

// ---------------- forward FFT of hb2 -> Xbf: 512 blocks, one packed FFT each ----------------
__global__ void k_fft_fwd(const f16* __restrict__ hb2, f16* __restrict__ Xbf,
                          const float2* __restrict__ tw) {
  __shared__ float2 z[2112];
  int tid = threadIdx.x;
  int b = blockIdx.x >> 8;
  int d0 = (blockIdx.x & 255) * 2;
  for (int t = tid; t < 1024; t += 256) {
    union { unsigned v; f16 q[2]; } w;
    w.v = *(const unsigned*)(hb2 + (size_t)(b * 1026 + 2 + t) * 512 + d0);
    z[zp(t)] = mkf2((float)w.q[0], (float)w.q[1]);
  }
  for (int t = 1024 + tid; t < 2048; t += 256) z[zp(t)] = mkf2(0.f, 0.f);
  __syncthreads();
  fft2048<false>(z, tw, tid);
  for (int f = tid; f <= 1024; f += 256) {
    float2 zf = z[zp(f)], zc = z[zp((2048 - f) & 2047)];
    float x0r = 0.5f * (zf.x + zc.x), x0i = 0.5f * (zf.y - zc.y);
    float x1r = 0.5f * (zf.y + zc.y), x1i = 0.5f * (zc.x - zf.x);
    union { f16 h2[2]; unsigned u; } pr, pi;
    pr.h2[0] = (f16)x0r; pr.h2[1] = (f16)x1r;
    pi.h2[0] = (f16)x0i; pi.h2[1] = (f16)x1i;
    if (f == 0) {
      *(unsigned*)(Xbf + (size_t)(b * RPB) * 512 + d0) = pr.u;           // DC (im=0)
    } else if (f == 1024) {
      *(unsigned*)(Xbf + (size_t)(b * RPB + 1) * 512 + d0) = pr.u;       // Nyquist (im=0)
    } else {
      *(unsigned*)(Xbf + (size_t)(b * RPB + 2 * f) * 512 + d0)     = pr.u;
      *(unsigned*)(Xbf + (size_t)(b * RPB + 2 * f + 1) * 512 + d0) = pi.u;
    }
  }
}

// ---------------- inverse FFT: sum of NPART f16 partials -> spec f16 (512 blocks) ----------------
__global__ void k_fft_inv(const f16* __restrict__ P, f16* __restrict__ spec,
                          const float2* __restrict__ tw) {
  __shared__ float2 z[2112];
  int tid = threadIdx.x;
  int b = blockIdx.x >> 8;
  int o0 = (blockIdx.x & 255) * 2;
  for (int fp = tid; fp < 512; fp += 256) {
    int f0 = fp * 2;
    size_t base0 = (size_t)o0 * RTOT + (size_t)b * RPB + 2 * f0;
    float s0r[2] = {0.f, 0.f}, s0i[2] = {0.f, 0.f};
    float s1r[2] = {0.f, 0.f}, s1i[2] = {0.f, 0.f};
#pragma unroll
    for (int g = 0; g < NPART; ++g) {
      const f16* Pg = P + (size_t)g * 512 * RTOT;
      union { uint2 u; f16 h[4]; } ua, uc;
      ua.u = *(const uint2*)(Pg + base0);
      uc.u = *(const uint2*)(Pg + base0 + RTOT);
      s0r[0] += (float)ua.h[0]; s0i[0] += (float)ua.h[1];
      s0r[1] += (float)ua.h[2]; s0i[1] += (float)ua.h[3];
      s1r[0] += (float)uc.h[0]; s1i[0] += (float)uc.h[1];
      s1r[1] += (float)uc.h[2]; s1i[1] += (float)uc.h[3];
    }
    if (fp == 0) {
      z[zp(0)]    = mkf2(s0r[0], s1r[0]);   // DC of both real o-channels
      z[zp(1024)] = mkf2(s0i[0], s1i[0]);   // Nyquist of both
    } else {
      z[zp(f0)]        = mkf2(s0r[0] - s1i[0], s0i[0] + s1r[0]);
      z[zp(2048 - f0)] = mkf2(s0r[0] + s1i[0], s1r[0] - s0i[0]);
    }
    int f1 = f0 + 1;
    z[zp(f1)]        = mkf2(s0r[1] - s1i[1], s0i[1] + s1r[1]);
    z[zp(2048 - f1)] = mkf2(s0r[1] + s1i[1], s1r[1] - s0i[1]);
  }
  __syncthreads();
  fft2048<true>(z, tw, tid);
  for (int t = tid; t < 1024; t += 256) {
    float2 v = z[zp(t)];
    union { f16 h[2]; unsigned u; } pk;
    pk.h[0] = (f16)v.x; pk.h[1] = (f16)v.y;
    *(unsigned*)(spec + (size_t)(b * 1024 + t) * 512 + o0) = pk.u;
  }
}

// ---------------- staging (shared by all GEMMs): global_load_lds, XOR-swizzled source ----------
template<int MODE, int MR, int NR>
__device__ __forceinline__ void stage(const f16* __restrict__ A, const f16* __restrict__ B0,
                                      int r0, int c0, int bz, int tid, int s,
                                      f16* As, f16* Bs) {
  constexpr int LDA = (MODE == 0) ? 512 : (MODE == 1) ? 1536 : (MODE == 2) ? 512 : 2048;
  const int kA = (MODE == 0) ? ((s & 7) * 64) : s * 64;
  const int rowl = tid >> 3;
  const int lc8 = ((tid & 7) ^ (rowl & 7)) * 8;   // swizzled chunk * 8 (f16)
  f16* lA = As + ((tid >> 6) << 9);               // wave-uniform LDS base
  f16* lB = Bs + ((tid >> 6) << 9);
#pragma unroll
  for (int i = 0; i < MR; ++i) {
    int row = i * 32 + rowl;
    gl16(A + (size_t)(r0 + row) * LDA + kA + lc8, lA + i * 2048);
  }
#pragma unroll
  for (int i = 0; i < NR; ++i) {
    int row = i * 32 + rowl;
    const f16* bs;
    if constexpr (MODE == 0) {
      int kb = bz * 4 + (s >> 3);
      bs = B0 + (size_t)(kb * 512 + c0 + row) * 512 + (s & 7) * 64 + lc8;
    } else if constexpr (MODE == 1) {
      int ip = s >> 3, d0 = (s & 7) * 64;
      int rr = c0 + row;
      int b = rr >> 10, t = rr & 1023;
      bs = B0 + (size_t)(b * 1026 + t + ip) * 512 + d0 + lc8;   // pad rows are zero
    } else {
      constexpr int LDB = (MODE == 2) ? 512 : 2048;
      bs = B0 + (size_t)(c0 + row) * LDB + s * 64 + lc8;
    }
    gl16(bs, lB + i * 2048);
  }
}

// ---------------- gemm0: spectral, 32x32x16 MFMA, 2x2 waves of 64x64 ----------------
// C/D layout (guide-verified m74/m101): col=lane&31, row=(reg&3)+8*(reg>>2)+4*(lane>>5).
// Reg quads (4jp..4jp+3) = rows (8jp..8jp+3)+4*(l>>5): two (re,im) f-slot pairs, contiguous.
__device__ __forceinline__ void mma_step32(const f16* As, const f16* Bs, int l, int wr, int wc,
                                           f32x16 acc[2][2]) {
  const int lr = l & 31, kg = l >> 5, sw = l & 7;
#pragma unroll
  for (int kk = 0; kk < 4; ++kk) {
    half8 af[2], bf[2];
    const int pc8 = (((kk * 2 + kg) ^ sw) << 3);
#pragma unroll
    for (int m = 0; m < 2; ++m)
      af[m] = *(const half8*)(As + (wr * 64 + m * 32 + lr) * 64 + pc8);
#pragma unroll
    for (int n = 0; n < 2; ++n)
      bf[n] = *(const half8*)(Bs + (wc * 64 + n * 32 + lr) * 64 + pc8);
#pragma unroll
    for (int m = 0; m < 2; ++m)
#pragma unroll
      for (int n = 0; n < 2; ++n)
        acc[m][n] = __builtin_amdgcn_mfma_f32_32x32x16_f16(af[m], bf[n], acc[m][n], 0, 0, 0);
  }
}

__global__ __launch_bounds__(256, 2)
void k_gemm0(const f16* __restrict__ A, const f16* __restrict__ B0,
             const float* __restrict__ aux0, f16* __restrict__ outP) {
  __shared__ __align__(16) f16 As[128 * 64];
  __shared__ __align__(16) f16 Bs[128 * 64];
  const int tid = threadIdx.x, l = tid & 63, wvi = tid >> 6;
  const int wr = wvi >> 1, wc = wvi & 1;
  int wg = (int)blockIdx.x;            // 1024 = 8 * 128, bijective XCD chunk swizzle
  wg = (wg & 7) * 128 + (wg >> 3);
  const int bz = wg >> 7; int rem = wg & 127;
  const int by = rem >> 2, bx = rem & 3;
  const int r0 = by * 128, c0 = bx * 128;
  const int kg32 = l >> 5;

  f32x16 acc[2][2], crun[2][2];
#pragma unroll
  for (int m = 0; m < 2; ++m)
#pragma unroll
    for (int n = 0; n < 2; ++n)
#pragma unroll
      for (int i = 0; i < 16; ++i) { acc[m][n][i] = 0.f; crun[m][n][i] = 0.f; }

  for (int s = 0; s < 32; ++s) {
    __syncthreads();                   // prior mma's LDS reads done
    stage<0, 4, 4>(A, B0, r0, c0, bz, tid, s, As, Bs);
    __syncthreads();                   // staging landed (compiler drains vmcnt)
    mma_step32(As, Bs, l, wr, wc, acc);
    if ((s & 7) == 7) {
      int kb = bz * 4 + (s >> 3);
#pragma unroll
      for (int m = 0; m < 2; ++m) {
#pragma unroll
        for (int jp = 0; jp < 4; ++jp) {
          int row_e = r0 + wr * 64 + m * 32 + jp * 8 + kg32 * 4;
          int rb = row_e & (RPB - 1);
          bool dc = (rb == 0);         // rows 0,1 = packed (DC.re, Nyq.re)
          float4 cs = *(const float4*)(aux0 + ((size_t)kb * CPS + (rb >> 1)) * 2);
          float t1 = dc ? 0.f : cs.y;
          float t2 = dc ? cs.y : cs.x;
#pragma unroll
          for (int n = 0; n < 2; ++n) {
            float pe0 = acc[m][n][4 * jp],     po0 = acc[m][n][4 * jp + 1];
            float pe1 = acc[m][n][4 * jp + 2], po1 = acc[m][n][4 * jp + 3];
            crun[m][n][4 * jp]     += cs.x * pe0 - t1 * po0;
            crun[m][n][4 * jp + 1] += t2 * po0 + t1 * pe0;
            crun[m][n][4 * jp + 2] += cs.z * pe1 - cs.w * po1;
            crun[m][n][4 * jp + 3] += cs.z * po1 + cs.w * pe1;
            acc[m][n][4 * jp] = 0.f;     acc[m][n][4 * jp + 1] = 0.f;
            acc[m][n][4 * jp + 2] = 0.f; acc[m][n][4 * jp + 3] = 0.f;
          }
        }
      }
    }
  }

  f16* P = outP + (size_t)bz * (512ull * RTOT);
#pragma unroll
  for (int m = 0; m < 2; ++m)
#pragma unroll
    for (int n = 0; n < 2; ++n) {
      int o = c0 + wc * 64 + n * 32 + (l & 31);
#pragma unroll
      for (int jp = 0; jp < 4; ++jp) {
        int Rb = r0 + wr * 64 + m * 32 + jp * 8 + kg32 * 4;
        union { f16 h[4]; uint2 u; } pk;
        pk.h[0] = (f16)crun[m][n][4 * jp];
        pk.h[1] = (f16)crun[m][n][4 * jp + 1];
        pk.h[2] = (f16)crun[m][n][4 * jp + 2];
        pk.h[3] = (f16)crun[m][n][4 * jp + 3];
        *(uint2*)(P + (size_t)o * RTOT + Rb) = pk.u;
      }
    }
}

// ---------------- generic MFMA GEMM (modes 1-3, 16x16x32, round-2 structure) ----------
template<int MR, int NR>
__device__ __forceinline__ void mma_step(const f16* As, const f16* Bs, int l, int wr, int wc,
                                         f32x4 acc[MR][NR]) {
  const int lr = l & 15, kg = l >> 4, sw = l & 7;
#pragma unroll
  for (int kk = 0; kk < 2; ++kk) {
    half8 af[MR], bf[NR];
    const int pc8 = (((kk * 4 + kg) ^ sw) << 3);
#pragma unroll
    for (int m = 0; m < MR; ++m)
      af[m] = *(const half8*)(As + (wr * (MR * 16) + m * 16 + lr) * 64 + pc8);
#pragma unroll
    for (int n = 0; n < NR; ++n)
      bf[n] = *(const half8*)(Bs + (wc * (NR * 16) + n * 16 + lr) * 64 + pc8);
#pragma unroll
    for (int m = 0; m < MR; ++m)
#pragma unroll
      for (int n = 0; n < NR; ++n)
        acc[m][n] = __builtin_amdgcn_mfma_f32_16x16x32_f16(af[m], bf[n], acc[m][n], 0, 0, 0);
  }
}

template<int MODE, int MR, int NR>
__global__ __launch_bounds__(256, (MODE == 2) ? 3 : 4)
void k_gemm(const f16* __restrict__ A, const f16* __restrict__ B0,
            const f16* auxA, const f16* auxB, f16* __restrict__ outH) {
  __shared__ __align__(16) f16 As[MR * 32 * 64];
  __shared__ __align__(16) f16 Bs[NR * 32 * 64];
  const int tid = threadIdx.x, l = tid & 63, wvi = tid >> 6;
  const int wr = wvi >> 1, wc = wvi & 1;
  const int bx = blockIdx.x, by = blockIdx.y;
  const int r0 = by * (MR * 32), c0 = bx * (NR * 32);
  constexpr int KS = (MODE == 1) ? 24 : (MODE == 2) ? 8 : 32;

  f32x4 acc[MR][NR];
  f32x4 zz = {0.f, 0.f, 0.f, 0.f};
#pragma unroll
  for (int m = 0; m < MR; ++m)
#pragma unroll
    for (int n = 0; n < NR; ++n) acc[m][n] = zz;

  for (int s = 0; s < KS; ++s) {
    __syncthreads();
    stage<MODE, MR, NR>(A, B0, r0, c0, 0, tid, s, As, Bs);
    __syncthreads();
    mma_step<MR, NR>(As, Bs, l, wr, wc, acc);
  }

  if constexpr (MODE == 1) {
#pragma unroll
    for (int m = 0; m < MR; ++m) {
      int o0 = r0 + wr * (MR * 16) + m * 16 + ((l >> 4) << 2);
#pragma unroll
      for (int n = 0; n < NR; ++n) {
        int r = c0 + wc * (NR * 16) + n * 16 + (l & 15);
        union { uint2 u; f16 h[4]; } xv, sv;
        xv.u = *(const uint2*)(auxA + (size_t)r * 512 + o0);
        sv.u = *(const uint2*)(auxB + (size_t)r * 512 + o0);
        f32x4 a = acc[m][n];
        union { f16 h[4]; uint2 u; } pk;
        pk.h[0] = (f16)((float)xv.h[0] + (float)sv.h[0] + a.x);
        pk.h[1] = (f16)((float)xv.h[1] + (float)sv.h[1] + a.y);
        pk.h[2] = (f16)((float)xv.h[2] + (float)sv.h[2] + a.z);
        pk.h[3] = (f16)((float)xv.h[3] + (float)sv.h[3] + a.w);
        *(uint2*)(outH + (size_t)r * 512 + o0) = pk.u;
      }
    }
  } else if constexpr (MODE == 2) {
#pragma unroll
    for (int m = 0; m < MR; ++m) {
      int jj0 = r0 + wr * (MR * 16) + m * 16 + ((l >> 4) << 2);
      int h2 = jj0 >> 1;
#pragma unroll
      for (int n = 0; n < NR; ++n) {
        int r = c0 + wc * (NR * 16) + n * 16 + (l & 15);
        f32x4 a = acc[m][n];
        float v0 = a.x * (a.y / (1.f + __expf(-a.y)));
        float v1 = a.z * (a.w / (1.f + __expf(-a.w)));
        union { f16 h[2]; unsigned u; } pk;
        pk.h[0] = (f16)v0; pk.h[1] = (f16)v1;
        *(unsigned*)(outH + (size_t)r * 2048 + h2) = pk.u;
      }
    }
  } else {
#pragma unroll
    for (int m = 0; m < MR; ++m) {
      int o0 = r0 + wr * (MR * 16) + m * 16 + ((l >> 4) << 2);
#pragma unroll
      for (int n = 0; n < NR; ++n) {
        int r = c0 + wc * (NR * 16) + n * 16 + (l & 15);
        union { uint2 u; f16 h[4]; } xv, x1v;
        xv.u  = *(const uint2*)(auxA + (size_t)r * 512 + o0);
        x1v.u = *(const uint2*)(auxB + (size_t)r * 512 + o0);
        f32x4 a = acc[m][n];
        union { f16 h[4]; uint2 u; } pk;
        pk.h[0] = (f16)((float)xv.h[0] + (float)x1v.h[0] + a.x);
        pk.h[1] = (f16)((float)xv.h[1] + (float)x1v.h[1] + a.y);
        pk.h[2] = (f16)((float)xv.h[2] + (float)x1v.h[2] + a.z);
        pk.h[3] = (f16)((float)xv.h[3] + (float)x1v.h[3] + a.w);
        *(uint2*)(outH + (size_t)r * 512 + o0) = pk.u;
      }
    }
  }
}

// ---------------- small projections ----------------
__global__ void k_inproj(const float* __restrict__ inp, const float* __restrict__ W,
                         f16* __restrict__ x) {
  __shared__ float row[64];
  int r = blockIdx.x, tid = threadIdx.x;
  if (tid < 64) row[tid] = inp[(size_t)r * 64 + tid];
  __syncthreads();
  for (int o = tid; o < 512; o += 256) {
    const float* wr = W + (size_t)o * 64;
    float acc = 0.f;
#pragma unroll 8
    for (int q = 0; q < 64; ++q) acc += row[q] * wr[q];
    x[(size_t)r * 512 + o] = (f16)acc;
  }
}

__global__ void k_outproj(const f16* __restrict__ x, const float* __restrict__ W,
                          float* out, int add) {
  __shared__ float row[512];
  int r = blockIdx.x, tid = threadIdx.x;
  for (int i = tid; i < 512; i += 256) row[i] = (float)x[(size_t)r * 512 + i];
  __syncthreads();
  int o = tid >> 2, part = tid & 3;
  const float* wr = W + (size_t)o * 512 + part * 128;
  const float* rp = row + part * 128;
  float acc = 0.f;
#pragma unroll 16
  for (int q = 0; q < 128; ++q) acc += rp[q] * wr[q];
  acc += __shfl_xor(acc, 1, 64);
  acc += __shfl_xor(acc, 2, 64);
  if (part == 0) {
    if (add) out[(size_t)r * 64 + o] += acc;
    else     out[(size_t)r * 64 + o] = acc;
  }
}

// ---------------- host ----------------
extern "C" void kernel_launch(void* const* d_in, const int* in_sizes, int n_in,
                              void* d_out, int out_size, void* d_ws, size_t ws_size,
                              hipStream_t stream) {
  const float* inputs    = (const float*)d_in[0];
  const float* sigma     = (const float*)d_in[1];
  const float* phi       = (const float*)d_in[2];
  const float* in_proj_w = (const float*)d_in[3];
  const float* rn_w      = (const float*)d_in[4];
  const float* M_u       = (const float*)d_in[5];
  const float* M_phi_p   = (const float*)d_in[6];
  const float* M_phi_m   = (const float*)d_in[7];
  const float* fc1       = (const float*)d_in[8];
  const float* fc2       = (const float*)d_in[9];
  const float* out_proj_w= (const float*)d_in[10];
  float* out = (float*)d_out;

  char* ws = (char*)d_ws;
  size_t off = 0;
  auto alloc = [&](size_t bytes) -> void* {
    void* p = ws + off;
    off += (bytes + 255) & ~(size_t)255;
    return p;
  };
  float2* tw   = (float2*)alloc(1024 * 8);
  float2* Vf   = (float2*)alloc((size_t)16 * 1025 * 8);
  float2* cpcm = (float2*)alloc((size_t)32 * CPS * 8);
  f16*    x    = (f16*)alloc((size_t)NROW * 512 * 2);
  f16*    hb2  = (f16*)alloc((size_t)2052 * 512 * 2);   // 2 batches x (2 pad + 1024) rows
  f16*    x1   = (f16*)alloc((size_t)NROW * 512 * 2);
  f16*    spec = (f16*)alloc((size_t)NROW * 512 * 2);
  f16*    Xbf  = (f16*)alloc((size_t)RTOT * 512 * 2);
  f16*    P    = (f16*)alloc((size_t)NPART * 512 * RTOT * 2);
  f16*    g1   = (f16*)alloc((size_t)NROW * 2048 * 2);
  f16*    Wsp  = (f16*)alloc((size_t)16384 * 512 * 2);
  f16*    Wu   = (f16*)alloc((size_t)512 * 1536 * 2);
  f16*    Wf1  = (f16*)alloc((size_t)4096 * 512 * 2);
  f16*    Wf2  = (f16*)alloc((size_t)512 * 2048 * 2);
  if (off > ws_size) return;  // workspace too small: fail loudly (output stays poisoned)

  // zero the AR window pad rows (rows 0,1 of each batch block in hb2)
  hipMemsetAsync(hb2, 0, 2 * 512 * sizeof(f16), stream);
  hipMemsetAsync(hb2 + (size_t)1026 * 512, 0, 2 * 512 * sizeof(f16), stream);
  k_twiddle<<<4, 256, 0, stream>>>(tw);
  k_fft_phi<<<8, 256, 0, stream>>>(phi, Vf, tw);
  k_cpcm<<<133, 256, 0, stream>>>(Vf, sigma, cpcm);

  for (int m = 0; m < 2; ++m) {
    k_inproj<<<NROW, 256, 0, stream>>>(inputs, in_proj_w + (size_t)m * 512 * 64, x);
    for (int li = 0; li < 2; ++li) {
      int ml = m * 2 + li;
      k_cast<<<3776, 256, 0, stream>>>(
          M_phi_p + (size_t)ml * 16 * 262144, M_phi_m + (size_t)ml * 16 * 262144,
          M_u + (size_t)ml * 3 * 262144, fc1 + (size_t)ml * 4096 * 512,
          fc2 + (size_t)ml * 512 * 2048, Wsp, Wu, Wf1, Wf2);
      k_rmsnorm<<<512, 256, 0, stream>>>(x, rn_w + (size_t)ml * 512, hb2);
      k_fft_fwd<<<512, 256, 0, stream>>>(hb2, Xbf, tw);
      k_gemm0<<<dim3(1024), 256, 0, stream>>>(Xbf, Wsp, (const float*)cpcm, P);
      k_fft_inv<<<512, 256, 0, stream>>>(P, spec, tw);
      k_gemm<1, 2, 2><<<dim3(32, 8), 256, 0, stream>>>(Wu, hb2, x, spec, x1);
      k_gemm<2, 4, 4><<<dim3(16, 32), 256, 0, stream>>>(Wf1, x1, nullptr, nullptr, g1);
      k_gemm<3, 2, 2><<<dim3(32, 8), 256, 0, stream>>>(Wf2, g1, x, x1, x);
    }
    k_outproj<<<NROW, 256, 0, stream>>>(x, out_proj_w + (size_t)m * 64 * 512, out, m);
  }
}

// Round 11
// 853.155 us; speedup vs baseline: 1.0974x; 1.0974x over previous
//
#include <hip/hip_runtime.h>
#include <hip/hip_bf16.h>

typedef _Float16 f16;
typedef _Float16 half8 __attribute__((ext_vector_type(8)));
typedef float f32x4 __attribute__((ext_vector_type(4)));

#define S_LEN 1024
#define DMODEL 512
#define NFFT   2048
#define RPB    2048     // rows per batch: f=1..1023 pairs + packed (DC.re, Nyq.re) in rows 0,1
#define RTOT   4096     // 2 batches -> exactly 32 row-tiles of 128
#define CPS    1064     // cpcm f-stride
#define NROW   2048     // B*S
#define NPART  4        // split-K partials for spectral GEMM (grid 512 = exactly 1 generation)

__device__ __forceinline__ float2 mkf2(float a, float b) { float2 r; r.x = a; r.y = b; return r; }
__device__ __forceinline__ int zp(int i) { return i + (i >> 5); }   // LDS bank-pad for FFT array

// async global->LDS (16B per lane). LDS dest must be wave-uniform base; lane writes at +lane*16.
__device__ __forceinline__ void gl16(const f16* g, f16* l) {
  __builtin_amdgcn_global_load_lds((const __attribute__((address_space(1))) void*)g,
                                   (__attribute__((address_space(3))) void*)l, 16, 0, 0);
}

// ---------------- FFT-2048 in LDS: fused radix-2^2, padded indexing ----------------
template<bool INV>
__device__ __forceinline__ void fft2048(float2* z, const float2* __restrict__ tw, int tid) {
  for (int i = tid; i < 2048; i += 256) {
    int j = (int)(__brev((unsigned)i) >> 21);
    if (i < j) { float2 a = z[zp(i)]; z[zp(i)] = z[zp(j)]; z[zp(j)] = a; }
  }
  __syncthreads();
#pragma unroll
  for (int sl = 1; sl <= 9; sl += 2) {    // fused stages (sl, sl+1)
    const int h = 1 << (sl - 1);
    for (int q = tid; q < 512; q += 256) {
      int j = q & (h - 1);
      int base = (q >> (sl - 1)) << (sl + 1);
      int i0 = base + j;
      float2 a0 = z[zp(i0)], a1 = z[zp(i0 + h)], a2 = z[zp(i0 + 2 * h)], a3 = z[zp(i0 + 3 * h)];
      float2 w1 = tw[j << (11 - sl)];
      float2 w2 = tw[j << (10 - sl)];
      float2 w3 = tw[(j + h) << (10 - sl)];
      if (INV) { w1.y = -w1.y; w2.y = -w2.y; w3.y = -w3.y; }
      float tr, ti;
      tr = a1.x * w1.x - a1.y * w1.y; ti = a1.x * w1.y + a1.y * w1.x;
      float2 b0 = mkf2(a0.x + tr, a0.y + ti), b1 = mkf2(a0.x - tr, a0.y - ti);
      tr = a3.x * w1.x - a3.y * w1.y; ti = a3.x * w1.y + a3.y * w1.x;
      float2 b2 = mkf2(a2.x + tr, a2.y + ti), b3 = mkf2(a2.x - tr, a2.y - ti);
      tr = b2.x * w2.x - b2.y * w2.y; ti = b2.x * w2.y + b2.y * w2.x;
      z[zp(i0)]         = mkf2(b0.x + tr, b0.y + ti);
      z[zp(i0 + 2 * h)] = mkf2(b0.x - tr, b0.y - ti);
      tr = b3.x * w3.x - b3.y * w3.y; ti = b3.x * w3.y + b3.y * w3.x;
      z[zp(i0 + h)]     = mkf2(b1.x + tr, b1.y + ti);
      z[zp(i0 + 3 * h)] = mkf2(b1.x - tr, b1.y - ti);
    }
    __syncthreads();
  }
  for (int j = tid; j < 1024; j += 256) {  // final radix-2 stage
    float2 w = tw[j];
    if (INV) w.y = -w.y;
    float2 a = z[zp(j)], b = z[zp(j + 1024)];
    float tr = b.x * w.x - b.y * w.y, ti = b.x * w.y + b.y * w.x;
    z[zp(j)]        = mkf2(a.x + tr, a.y + ti);
    z[zp(j + 1024)] = mkf2(a.x - tr, a.y - ti);
  }
  __syncthreads();
}

// ---------------- init kernels ----------------
__global__ void k_twiddle(float2* tw) {
  int i = blockIdx.x * 256 + threadIdx.x;
  if (i < 1024) {
    float ang = -6.2831853071795864769f * (float)i / 2048.0f;
    tw[i] = mkf2(cosf(ang), sinf(ang));
  }
}

// rfft of phi columns (pairs packed into one complex FFT)
__global__ void k_fft_phi(const float* __restrict__ phi, float2* __restrict__ Vf,
                          const float2* __restrict__ tw) {
  __shared__ float2 z[2112];
  int tid = threadIdx.x;
  int k0 = blockIdx.x * 2;
  for (int t = tid; t < 1024; t += 256)
    z[zp(t)] = *(const float2*)(phi + (size_t)t * 16 + k0);
  for (int t = 1024 + tid; t < 2048; t += 256) z[zp(t)] = mkf2(0.f, 0.f);
  __syncthreads();
  fft2048<false>(z, tw, tid);
  for (int f = tid; f <= 1024; f += 256) {
    float2 zf = z[zp(f)], zc = z[zp((2048 - f) & 2047)];
    Vf[(size_t)k0 * 1025 + f]       = mkf2(0.5f * (zf.x + zc.x), 0.5f * (zf.y - zc.y));
    Vf[(size_t)(k0 + 1) * 1025 + f] = mkf2(0.5f * (zf.y + zc.y), 0.5f * (zc.x - zf.x));
  }
}

// cpcm[kb][f]: f=1..1023 standard complex scale; slot 0 packs (c_DC, c_Nyq) (both REAL).
__global__ void k_cpcm(const float2* __restrict__ Vf, const float* __restrict__ sigma,
                       float2* __restrict__ cpcm) {
  int idx = blockIdx.x * 256 + threadIdx.x;
  if (idx >= 32 * CPS) return;
  int kb = idx / CPS, f = idx - kb * CPS;
  int k = kb & 15;
  float s = powf(sigma[k], 0.25f) * (1.0f / 2048.0f);
  float2 v = mkf2(0.f, 0.f);
  if (f == 0) {
    float dc = Vf[(size_t)k * 1025].x;          // real
    float ny = Vf[(size_t)k * 1025 + 1024].x;   // real
    v = (kb < 16) ? mkf2(s * dc, s * ny) : mkf2(s * ny, s * dc);
  } else if (f <= 1023) {
    if (kb < 16) {
      v = Vf[(size_t)k * 1025 + f];
    } else {
      float2 t = Vf[(size_t)k * 1025 + (1024 - f)];
      v = mkf2(t.x, -t.y);
    }
    v.x *= s; v.y *= s;
  }
  cpcm[idx] = v;
}

// ---------------- per-layer weight cast/transpose ----------------
__global__ void k_cast(const float* __restrict__ mp, const float* __restrict__ mm,
                       const float* __restrict__ mu, const float* __restrict__ fc1,
                       const float* __restrict__ fc2,
                       f16* __restrict__ Wsp, f16* __restrict__ Wu,
                       f16* __restrict__ Wf1, f16* __restrict__ Wf2) {
  __shared__ float T[64][65];
  int blk = blockIdx.x, tid = threadIdx.x;
  if (blk < 2048) {                    // Wsp: Wsp[(kb*512+o)][d] = m?[k][d][o]
    int mat = blk >> 6, tile = blk & 63;
    int d0 = (tile >> 3) * 64, o0 = (tile & 7) * 64;
    const float* src = (mat < 16) ? (mp + (size_t)mat * 262144)
                                  : (mm + (size_t)(mat - 16) * 262144);
    for (int q = tid; q < 4096; q += 256) {
      int i = q >> 6, j = q & 63;
      T[i][j] = src[(size_t)(d0 + i) * 512 + o0 + j];
    }
    __syncthreads();
    for (int q = tid; q < 4096; q += 256) {
      int i = q >> 6, j = q & 63;
      Wsp[(size_t)(mat * 512 + o0 + i) * 512 + d0 + j] = (f16)T[j][i];
    }
  } else if (blk < 2240) {             // Wu: Wu[o][ip*512+d] = mu[2-ip][d][o]
    int q0 = blk - 2048;
    int ip = q0 >> 6, tile = q0 & 63;
    int d0 = (tile >> 3) * 64, o0 = (tile & 7) * 64;
    const float* src = mu + (size_t)(2 - ip) * 262144;
    for (int q = tid; q < 4096; q += 256) {
      int i = q >> 6, j = q & 63;
      T[i][j] = src[(size_t)(d0 + i) * 512 + o0 + j];
    }
    __syncthreads();
    for (int q = tid; q < 4096; q += 256) {
      int i = q >> 6, j = q & 63;
      Wu[(size_t)(o0 + i) * 1536 + ip * 512 + d0 + j] = (f16)T[j][i];
    }
  } else if (blk < 3264) {             // fc1 perm copy: row 2h = y-row h, 2h+1 = gate-row h
    int q0 = blk - 2240;
    size_t e = ((size_t)q0 * 256 + tid) * 8;
    int jj = (int)(e >> 9), col = (int)(e & 511);
    int srow = (jj & 1) ? (2048 + (jj >> 1)) : (jj >> 1);
    const float4* s = (const float4*)(fc1 + (size_t)srow * 512 + col);
    float4 a = s[0], b = s[1];
    union { f16 h[8]; uint4 u; } pk;
    pk.h[0] = (f16)a.x; pk.h[1] = (f16)a.y; pk.h[2] = (f16)a.z; pk.h[3] = (f16)a.w;
    pk.h[4] = (f16)b.x; pk.h[5] = (f16)b.y; pk.h[6] = (f16)b.z; pk.h[7] = (f16)b.w;
    *(uint4*)(Wf1 + (size_t)jj * 512 + col) = pk.u;
  } else {                             // fc2 straight copy (already [o][j])
    int q0 = blk - 3264;
    size_t e = ((size_t)q0 * 256 + tid) * 8;
    const float4* s = (const float4*)(fc2 + e);
    float4 a = s[0], b = s[1];
    union { f16 h[8]; uint4 u; } pk;
    pk.h[0] = (f16)a.x; pk.h[1] = (f16)a.y; pk.h[2] = (f16)a.z; pk.h[3] = (f16)a.w;
    pk.h[4] = (f16)b.x; pk.h[5] = (f16)b.y; pk.h[6] = (f16)b.z; pk.h[7] = (f16)b.w;
    *(uint4*)(Wf2 + e) = pk.u;
  }
}

// ---------------- rmsnorm (f16 x in, zero-padded fp16 hb2 out) ----------------
__global__ void k_rmsnorm(const f16* __restrict__ x, const float* __restrict__ w,
                          f16* __restrict__ hb2) {
  int tid = threadIdx.x, l = tid & 63, wv = tid >> 6;
  int r = blockIdx.x * 4 + wv;
  int b = r >> 10, t = r & 1023;
  const f16* xr = x + (size_t)r * 512;
  f16* hr = hb2 + (size_t)(b * 1026 + 2 + t) * 512;
  float v[8]; float ss = 0.f;
#pragma unroll
  for (int j = 0; j < 8; ++j) { v[j] = (float)xr[j * 64 + l]; ss += v[j] * v[j]; }
#pragma unroll
  for (int o = 32; o; o >>= 1) ss += __shfl_xor(ss, o, 64);
  float rn = rsqrtf(ss * (1.f / 512.f) + 1e-5f);
#pragma unroll
  for (int j = 0; j < 8; ++j) {
    float hv = v[j] * rn * w[j * 64 + l];
    hr[j * 64 + l] = (f16)hv;
  }
}

// ---------------- forward FFT of hb2 -> Xbf: 512 blocks, one packed FFT each ----------------
__global__ void k_fft_fwd(const f16* __restrict__ hb2, f16* __restrict__ Xbf,
                          const float2* __restrict__ tw) {
  __shared__ float2 z[2112];
  int tid = threadIdx.x;
  int b = blockIdx.x >> 8;
  int d0 = (blockIdx.x & 255) * 2;
  for (int t = tid; t < 1024; t += 256) {
    union { unsigned v; f16 q[2]; } w;
    w.v = *(const unsigned*)(hb2 + (size_t)(b * 1026 + 2 + t) * 512 + d0);
    z[zp(t)] = mkf2((float)w.q[0], (float)w.q[1]);
  }
  for (int t = 1024 + tid; t < 2048; t += 256) z[zp(t)] = mkf2(0.f, 0.f);
  __syncthreads();
  fft2048<false>(z, tw, tid);
  for (int f = tid; f <= 1024; f += 256) {
    float2 zf = z[zp(f)], zc = z[zp((2048 - f) & 2047)];
    float x0r = 0.5f * (zf.x + zc.x), x0i = 0.5f * (zf.y - zc.y);
    float x1r = 0.5f * (zf.y + zc.y), x1i = 0.5f * (zc.x - zf.x);
    union { f16 h2[2]; unsigned u; } pr, pi;
    pr.h2[0] = (f16)x0r; pr.h2[1] = (f16)x1r;
    pi.h2[0] = (f16)x0i; pi.h2[1] = (f16)x1i;
    if (f == 0) {
      *(unsigned*)(Xbf + (size_t)(b * RPB) * 512 + d0) = pr.u;           // DC (im=0)
    } else if (f == 1024) {
      *(unsigned*)(Xbf + (size_t)(b * RPB + 1) * 512 + d0) = pr.u;       // Nyquist (im=0)
    } else {
      *(unsigned*)(Xbf + (size_t)(b * RPB + 2 * f) * 512 + d0)     = pr.u;
      *(unsigned*)(Xbf + (size_t)(b * RPB + 2 * f + 1) * 512 + d0) = pi.u;
    }
  }
}

// ---------------- inverse FFT: sum of NPART f16 partials -> spec f16 (512 blocks) ----------------
__global__ void k_fft_inv(const f16* __restrict__ P, f16* __restrict__ spec,
                          const float2* __restrict__ tw) {
  __shared__ float2 z[2112];
  int tid = threadIdx.x;
  int b = blockIdx.x >> 8;
  int o0 = (blockIdx.x & 255) * 2;
  for (int fp = tid; fp < 512; fp += 256) {
    int f0 = fp * 2;
    size_t base0 = (size_t)o0 * RTOT + (size_t)b * RPB + 2 * f0;
    float s0r[2] = {0.f, 0.f}, s0i[2] = {0.f, 0.f};
    float s1r[2] = {0.f, 0.f}, s1i[2] = {0.f, 0.f};
#pragma unroll
    for (int g = 0; g < NPART; ++g) {
      const f16* Pg = P + (size_t)g * 512 * RTOT;
      union { uint2 u; f16 h[4]; } ua, uc;
      ua.u = *(const uint2*)(Pg + base0);
      uc.u = *(const uint2*)(Pg + base0 + RTOT);
      s0r[0] += (float)ua.h[0]; s0i[0] += (float)ua.h[1];
      s0r[1] += (float)ua.h[2]; s0i[1] += (float)ua.h[3];
      s1r[0] += (float)uc.h[0]; s1i[0] += (float)uc.h[1];
      s1r[1] += (float)uc.h[2]; s1i[1] += (float)uc.h[3];
    }
    if (fp == 0) {
      z[zp(0)]    = mkf2(s0r[0], s1r[0]);   // DC of both real o-channels
      z[zp(1024)] = mkf2(s0i[0], s1i[0]);   // Nyquist of both
    } else {
      z[zp(f0)]        = mkf2(s0r[0] - s1i[0], s0i[0] + s1r[0]);
      z[zp(2048 - f0)] = mkf2(s0r[0] + s1i[0], s1r[0] - s0i[0]);
    }
    int f1 = f0 + 1;
    z[zp(f1)]        = mkf2(s0r[1] - s1i[1], s0i[1] + s1r[1]);
    z[zp(2048 - f1)] = mkf2(s0r[1] + s1i[1], s1r[1] - s0i[1]);
  }
  __syncthreads();
  fft2048<true>(z, tw, tid);
  for (int t = tid; t < 1024; t += 256) {
    float2 v = z[zp(t)];
    union { f16 h[2]; unsigned u; } pk;
    pk.h[0] = (f16)v.x; pk.h[1] = (f16)v.y;
    *(unsigned*)(spec + (size_t)(b * 1024 + t) * 512 + o0) = pk.u;
  }
}

// ---------------- unified MFMA GEMM: round-2 structure, 16x16x32 (measured best) ----------
// Flat s-loop, single 32KB LDS buffer, two __syncthreads per step. Do NOT unroll /
// double-buffer / vmcnt / raise occupancy / 32x32 MFMA (r3=135, r4=191, r5=363, r6=167,
// r10 32x32=111 w/ 8.4M bank conflicts — vs this structure's 98us at 0 conflicts).
// MODE 0: spectral  A=Xbf  B=Wsp (kb loop, complex-scale; DC/Nyq packed row fix) -> P[g] f16
// MODE 1: AR        A=Wu   B=hb2 window -> x1 = x + spec + acc (f16)
// MODE 2: MLP1      A=fc1p B=x1 -> g1 = y*silu(gate) (f16)
// MODE 3: MLP2      A=fc2  B=g1 -> x = x + x1 + acc (f16)
template<int MODE, int MR, int NR>
__device__ __forceinline__ void stage(const f16* __restrict__ A, const f16* __restrict__ B0,
                                      int r0, int c0, int bz, int tid, int s,
                                      f16* As, f16* Bs) {
  constexpr int LDA = (MODE == 0) ? 512 : (MODE == 1) ? 1536 : (MODE == 2) ? 512 : 2048;
  const int kA = (MODE == 0) ? ((s & 7) * 64) : s * 64;
  const int rowl = tid >> 3;
  const int lc8 = ((tid & 7) ^ (rowl & 7)) * 8;   // swizzled chunk * 8 (f16)
  f16* lA = As + ((tid >> 6) << 9);               // wave-uniform LDS base
  f16* lB = Bs + ((tid >> 6) << 9);
#pragma unroll
  for (int i = 0; i < MR; ++i) {
    int row = i * 32 + rowl;
    gl16(A + (size_t)(r0 + row) * LDA + kA + lc8, lA + i * 2048);
  }
#pragma unroll
  for (int i = 0; i < NR; ++i) {
    int row = i * 32 + rowl;
    const f16* bs;
    if constexpr (MODE == 0) {
      int kb = bz * 8 + (s >> 3);
      bs = B0 + (size_t)(kb * 512 + c0 + row) * 512 + (s & 7) * 64 + lc8;
    } else if constexpr (MODE == 1) {
      int ip = s >> 3, d0 = (s & 7) * 64;
      int rr = c0 + row;
      int b = rr >> 10, t = rr & 1023;
      bs = B0 + (size_t)(b * 1026 + t + ip) * 512 + d0 + lc8;   // pad rows are zero
    } else {
      constexpr int LDB = (MODE == 2) ? 512 : 2048;
      bs = B0 + (size_t)(c0 + row) * LDB + s * 64 + lc8;
    }
    gl16(bs, lB + i * 2048);
  }
}

template<int MR, int NR>
__device__ __forceinline__ void mma_step(const f16* As, const f16* Bs, int l, int wr, int wc,
                                         f32x4 acc[MR][NR]) {
  const int lr = l & 15, kg = l >> 4, sw = l & 7;
#pragma unroll
  for (int kk = 0; kk < 2; ++kk) {
    half8 af[MR], bf[NR];
    const int pc8 = (((kk * 4 + kg) ^ sw) << 3);
#pragma unroll
    for (int m = 0; m < MR; ++m)
      af[m] = *(const half8*)(As + (wr * (MR * 16) + m * 16 + lr) * 64 + pc8);
#pragma unroll
    for (int n = 0; n < NR; ++n)
      bf[n] = *(const half8*)(Bs + (wc * (NR * 16) + n * 16 + lr) * 64 + pc8);
#pragma unroll
    for (int m = 0; m < MR; ++m)
#pragma unroll
      for (int n = 0; n < NR; ++n)
        acc[m][n] = __builtin_amdgcn_mfma_f32_16x16x32_f16(af[m], bf[n], acc[m][n], 0, 0, 0);
  }
}

template<int MODE, int MR, int NR>
__global__ __launch_bounds__(256, (MODE == 0) ? 2 : ((MODE == 2) ? 3 : 4))
void k_gemm(const f16* __restrict__ A, const f16* __restrict__ B0,
            const float* __restrict__ aux0, const f16* auxA, const f16* auxB,
            f16* __restrict__ outH) {
  __shared__ __align__(16) f16 As[MR * 32 * 64];
  __shared__ __align__(16) f16 Bs[NR * 32 * 64];
  const int tid = threadIdx.x, l = tid & 63, wvi = tid >> 6;
  const int wr = wvi >> 1, wc = wvi & 1;
  int bx, by, bz;
  if constexpr (MODE == 0) {           // 1D grid of 512 = 8 * 64, bijective XCD chunk swizzle
    int wg = (int)blockIdx.x;
    wg = (wg & 7) * 64 + (wg >> 3);
    bz = wg >> 7; int rem = wg & 127;
    by = rem >> 2; bx = rem & 3;
  } else { bx = blockIdx.x; by = blockIdx.y; bz = 0; }
  const int r0 = by * (MR * 32), c0 = bx * (NR * 32);
  constexpr int KS = (MODE == 0) ? 64 : (MODE == 1) ? 24 : (MODE == 2) ? 8 : 32;

  f32x4 acc[MR][NR];
  f32x4 crun[MR][NR];
  f32x4 zz = {0.f, 0.f, 0.f, 0.f};
#pragma unroll
  for (int m = 0; m < MR; ++m)
#pragma unroll
    for (int n = 0; n < NR; ++n) { acc[m][n] = zz; crun[m][n] = zz; }

  for (int s = 0; s < KS; ++s) {
    __syncthreads();                   // prior mma's LDS reads done
    stage<MODE, MR, NR>(A, B0, r0, c0, bz, tid, s, As, Bs);
    __syncthreads();                   // staging landed (compiler drains vmcnt)
    mma_step<MR, NR>(As, Bs, l, wr, wc, acc);
    if constexpr (MODE == 0) {
      if ((s & 7) == 7) {
        int kb = bz * 8 + (s >> 3);
#pragma unroll
        for (int m = 0; m < MR; ++m) {
          int R = r0 + wr * (MR * 16) + m * 16 + ((l >> 4) << 2);
          int rb = R & (RPB - 1);
          bool dc = (rb == 0);         // rows 0,1 = packed (DC.re, Nyq.re): scale separately
          float4 cs = *(const float4*)(aux0 + (size_t)kb * (CPS * 2) + (rb >> 1) * 2);
          float t1 = dc ? 0.f : cs.y;
          float t2 = dc ? cs.y : cs.x;
#pragma unroll
          for (int n = 0; n < NR; ++n) {
            f32x4 p = acc[m][n];
            crun[m][n].x += cs.x * p.x - t1 * p.y;
            crun[m][n].y += t2 * p.y + t1 * p.x;
            crun[m][n].z += cs.z * p.z - cs.w * p.w;
            crun[m][n].w += cs.z * p.w + cs.w * p.z;
            acc[m][n] = zz;
          }
        }
      }
    }
  }

  if constexpr (MODE == 0) {
    f16* P = outH + (size_t)bz * (512ull * RTOT);
#pragma unroll
    for (int m = 0; m < MR; ++m) {
      int R0 = r0 + wr * (MR * 16) + m * 16 + ((l >> 4) << 2);
#pragma unroll
      for (int n = 0; n < NR; ++n) {
        int o = c0 + wc * (NR * 16) + n * 16 + (l & 15);
        union { f16 h[4]; uint2 u; } pk;
        pk.h[0] = (f16)crun[m][n].x; pk.h[1] = (f16)crun[m][n].y;
        pk.h[2] = (f16)crun[m][n].z; pk.h[3] = (f16)crun[m][n].w;
        *(uint2*)(P + (size_t)o * RTOT + R0) = pk.u;
      }
    }
  } else if constexpr (MODE == 1) {
#pragma unroll
    for (int m = 0; m < MR; ++m) {
      int o0 = r0 + wr * (MR * 16) + m * 16 + ((l >> 4) << 2);
#pragma unroll
      for (int n = 0; n < NR; ++n) {
        int r = c0 + wc * (NR * 16) + n * 16 + (l & 15);
        union { uint2 u; f16 h[4]; } xv, sv;
        xv.u = *(const uint2*)(auxA + (size_t)r * 512 + o0);
        sv.u = *(const uint2*)(auxB + (size_t)r * 512 + o0);
        f32x4 a = acc[m][n];
        union { f16 h[4]; uint2 u; } pk;
        pk.h[0] = (f16)((float)xv.h[0] + (float)sv.h[0] + a.x);
        pk.h[1] = (f16)((float)xv.h[1] + (float)sv.h[1] + a.y);
        pk.h[2] = (f16)((float)xv.h[2] + (float)sv.h[2] + a.z);
        pk.h[3] = (f16)((float)xv.h[3] + (float)sv.h[3] + a.w);
        *(uint2*)(outH + (size_t)r * 512 + o0) = pk.u;
      }
    }
  } else if constexpr (MODE == 2) {
#pragma unroll
    for (int m = 0; m < MR; ++m) {
      int jj0 = r0 + wr * (MR * 16) + m * 16 + ((l >> 4) << 2);
      int h2 = jj0 >> 1;
#pragma unroll
      for (int n = 0; n < NR; ++n) {
        int r = c0 + wc * (NR * 16) + n * 16 + (l & 15);
        f32x4 a = acc[m][n];
        float v0 = a.x * (a.y / (1.f + __expf(-a.y)));
        float v1 = a.z * (a.w / (1.f + __expf(-a.w)));
        union { f16 h[2]; unsigned u; } pk;
        pk.h[0] = (f16)v0; pk.h[1] = (f16)v1;
        *(unsigned*)(outH + (size_t)r * 2048 + h2) = pk.u;
      }
    }
  } else {
#pragma unroll
    for (int m = 0; m < MR; ++m) {
      int o0 = r0 + wr * (MR * 16) + m * 16 + ((l >> 4) << 2);
#pragma unroll
      for (int n = 0; n < NR; ++n) {
        int r = c0 + wc * (NR * 16) + n * 16 + (l & 15);
        union { uint2 u; f16 h[4]; } xv, x1v;
        xv.u  = *(const uint2*)(auxA + (size_t)r * 512 + o0);
        x1v.u = *(const uint2*)(auxB + (size_t)r * 512 + o0);
        f32x4 a = acc[m][n];
        union { f16 h[4]; uint2 u; } pk;
        pk.h[0] = (f16)((float)xv.h[0] + (float)x1v.h[0] + a.x);
        pk.h[1] = (f16)((float)xv.h[1] + (float)x1v.h[1] + a.y);
        pk.h[2] = (f16)((float)xv.h[2] + (float)x1v.h[2] + a.z);
        pk.h[3] = (f16)((float)xv.h[3] + (float)x1v.h[3] + a.w);
        *(uint2*)(outH + (size_t)r * 512 + o0) = pk.u;
      }
    }
  }
}

// ---------------- small projections ----------------
__global__ void k_inproj(const float* __restrict__ inp, const float* __restrict__ W,
                         f16* __restrict__ x) {
  __shared__ float row[64];
  int r = blockIdx.x, tid = threadIdx.x;
  if (tid < 64) row[tid] = inp[(size_t)r * 64 + tid];
  __syncthreads();
  for (int o = tid; o < 512; o += 256) {
    const float* wr = W + (size_t)o * 64;
    float acc = 0.f;
#pragma unroll 8
    for (int q = 0; q < 64; ++q) acc += row[q] * wr[q];
    x[(size_t)r * 512 + o] = (f16)acc;
  }
}

__global__ void k_outproj(const f16* __restrict__ x, const float* __restrict__ W,
                          float* out, int add) {
  __shared__ float row[512];
  int r = blockIdx.x, tid = threadIdx.x;
  for (int i = tid; i < 512; i += 256) row[i] = (float)x[(size_t)r * 512 + i];
  __syncthreads();
  int o = tid >> 2, part = tid & 3;
  const float* wr = W + (size_t)o * 512 + part * 128;
  const float* rp = row + part * 128;
  float acc = 0.f;
#pragma unroll 16
  for (int q = 0; q < 128; ++q) acc += rp[q] * wr[q];
  acc += __shfl_xor(acc, 1, 64);
  acc += __shfl_xor(acc, 2, 64);
  if (part == 0) {
    if (add) out[(size_t)r * 64 + o] += acc;
    else     out[(size_t)r * 64 + o] = acc;
  }
}

// ---------------- host ----------------
extern "C" void kernel_launch(void* const* d_in, const int* in_sizes, int n_in,
                              void* d_out, int out_size, void* d_ws, size_t ws_size,
                              hipStream_t stream) {
  const float* inputs    = (const float*)d_in[0];
  const float* sigma     = (const float*)d_in[1];
  const float* phi       = (const float*)d_in[2];
  const float* in_proj_w = (const float*)d_in[3];
  const float* rn_w      = (const float*)d_in[4];
  const float* M_u       = (const float*)d_in[5];
  const float* M_phi_p   = (const float*)d_in[6];
  const float* M_phi_m   = (const float*)d_in[7];
  const float* fc1       = (const float*)d_in[8];
  const float* fc2       = (const float*)d_in[9];
  const float* out_proj_w= (const float*)d_in[10];
  float* out = (float*)d_out;

  char* ws = (char*)d_ws;
  size_t off = 0;
  auto alloc = [&](size_t bytes) -> void* {
    void* p = ws + off;
    off += (bytes + 255) & ~(size_t)255;
    return p;
  };
  float2* tw   = (float2*)alloc(1024 * 8);
  float2* Vf   = (float2*)alloc((size_t)16 * 1025 * 8);
  float2* cpcm = (float2*)alloc((size_t)32 * CPS * 8);
  f16*    x    = (f16*)alloc((size_t)NROW * 512 * 2);
  f16*    hb2  = (f16*)alloc((size_t)2052 * 512 * 2);   // 2 batches x (2 pad + 1024) rows
  f16*    x1   = (f16*)alloc((size_t)NROW * 512 * 2);
  f16*    spec = (f16*)alloc((size_t)NROW * 512 * 2);
  f16*    Xbf  = (f16*)alloc((size_t)RTOT * 512 * 2);
  f16*    P    = (f16*)alloc((size_t)NPART * 512 * RTOT * 2);
  f16*    g1   = (f16*)alloc((size_t)NROW * 2048 * 2);
  f16*    Wsp  = (f16*)alloc((size_t)16384 * 512 * 2);
  f16*    Wu   = (f16*)alloc((size_t)512 * 1536 * 2);
  f16*    Wf1  = (f16*)alloc((size_t)4096 * 512 * 2);
  f16*    Wf2  = (f16*)alloc((size_t)512 * 2048 * 2);
  if (off > ws_size) return;  // workspace too small: fail loudly (output stays poisoned)

  // zero the AR window pad rows (rows 0,1 of each batch block in hb2)
  hipMemsetAsync(hb2, 0, 2 * 512 * sizeof(f16), stream);
  hipMemsetAsync(hb2 + (size_t)1026 * 512, 0, 2 * 512 * sizeof(f16), stream);
  k_twiddle<<<4, 256, 0, stream>>>(tw);
  k_fft_phi<<<8, 256, 0, stream>>>(phi, Vf, tw);
  k_cpcm<<<133, 256, 0, stream>>>(Vf, sigma, cpcm);

  for (int m = 0; m < 2; ++m) {
    k_inproj<<<NROW, 256, 0, stream>>>(inputs, in_proj_w + (size_t)m * 512 * 64, x);
    for (int li = 0; li < 2; ++li) {
      int ml = m * 2 + li;
      k_cast<<<3776, 256, 0, stream>>>(
          M_phi_p + (size_t)ml * 16 * 262144, M_phi_m + (size_t)ml * 16 * 262144,
          M_u + (size_t)ml * 3 * 262144, fc1 + (size_t)ml * 4096 * 512,
          fc2 + (size_t)ml * 512 * 2048, Wsp, Wu, Wf1, Wf2);
      k_rmsnorm<<<512, 256, 0, stream>>>(x, rn_w + (size_t)ml * 512, hb2);
      k_fft_fwd<<<512, 256, 0, stream>>>(hb2, Xbf, tw);
      k_gemm<0, 4, 4><<<dim3(512), 256, 0, stream>>>(Xbf, Wsp, (const float*)cpcm,
                                                     nullptr, nullptr, P);
      k_fft_inv<<<512, 256, 0, stream>>>(P, spec, tw);
      k_gemm<1, 2, 2><<<dim3(32, 8), 256, 0, stream>>>(Wu, hb2, nullptr, x, spec, x1);
      k_gemm<2, 4, 4><<<dim3(16, 32), 256, 0, stream>>>(Wf1, x1, nullptr,
                                                        nullptr, nullptr, g1);
      k_gemm<3, 2, 2><<<dim3(32, 8), 256, 0, stream>>>(Wf2, g1, nullptr, x, x1, x);
    }
    k_outproj<<<NROW, 256, 0, stream>>>(x, out_proj_w + (size_t)m * 64 * 512, out, m);
  }
}

// Round 12
// 827.560 us; speedup vs baseline: 1.1314x; 1.0309x over previous
//
#include <hip/hip_runtime.h>
#include <hip/hip_bf16.h>

typedef _Float16 f16;
typedef _Float16 half8 __attribute__((ext_vector_type(8)));
typedef float f32x4 __attribute__((ext_vector_type(4)));

#define S_LEN 1024
#define DMODEL 512
#define NFFT   2048
#define RPB    2048     // rows per batch: f=1..1023 pairs + packed (DC.re, Nyq.re) in rows 0,1
#define RTOT   4096     // 2 batches -> exactly 32 row-tiles of 128
#define CPS    1064     // cpcm f-stride
#define NROW   2048     // B*S
#define NPART  4        // split-K partials for spectral GEMM (grid 512 = exactly 1 generation)

__device__ __forceinline__ float2 mkf2(float a, float b) { float2 r; r.x = a; r.y = b; return r; }
__device__ __forceinline__ int zp(int i) { return i + (i >> 5); }   // LDS bank-pad for FFT array
__device__ __forceinline__ float2 cmul(float2 w, float2 b) {
  return mkf2(b.x * w.x - b.y * w.y, b.x * w.y + b.y * w.x);
}
__device__ __forceinline__ float2 f2a(float2 a, float2 b) { return mkf2(a.x + b.x, a.y + b.y); }
__device__ __forceinline__ float2 f2s(float2 a, float2 b) { return mkf2(a.x - b.x, a.y - b.y); }

// async global->LDS (16B per lane). LDS dest must be wave-uniform base; lane writes at +lane*16.
__device__ __forceinline__ void gl16(const f16* g, f16* l) {
  __builtin_amdgcn_global_load_lds((const __attribute__((address_space(1))) void*)g,
                                   (__attribute__((address_space(3))) void*)l, 16, 0, 0);
}

// ---------------- FFT-2048 in LDS: 3x radix-8 + 1x radix-4, padded indexing ----------------
// 5 LDS rounds total (bitrev + 3 + 1) vs 7 for radix-2^2.
template<bool INV>
__device__ __forceinline__ void fft2048(float2* z, const float2* __restrict__ tw, int tid) {
  for (int i = tid; i < 2048; i += 256) {
    int j = (int)(__brev((unsigned)i) >> 21);
    if (i < j) { float2 a = z[zp(i)]; z[zp(i)] = z[zp(j)]; z[zp(j)] = a; }
  }
  __syncthreads();
#pragma unroll
  for (int r8 = 0; r8 < 3; ++r8) {       // fused stages (1,2,3),(4,5,6),(7,8,9)
    const int sl = 1 + 3 * r8;
    const int h = 1 << (sl - 1);
    {
      int q = tid;                        // 256 groups of 8, one per thread
      int j = q & (h - 1);
      int i0 = ((q >> (sl - 1)) << (sl + 2)) + j;
      float2 a0 = z[zp(i0)],         a1 = z[zp(i0 + h)];
      float2 a2 = z[zp(i0 + 2 * h)], a3 = z[zp(i0 + 3 * h)];
      float2 a4 = z[zp(i0 + 4 * h)], a5 = z[zp(i0 + 5 * h)];
      float2 a6 = z[zp(i0 + 6 * h)], a7 = z[zp(i0 + 7 * h)];
      float2 wA  = tw[j << (11 - sl)];
      float2 wB0 = tw[j << (10 - sl)];
      float2 wB1 = tw[(j + h) << (10 - sl)];
      float2 wC0 = tw[j << (9 - sl)];
      float2 wC1 = tw[(j + h) << (9 - sl)];
      float2 wC2 = tw[(j + 2 * h) << (9 - sl)];
      float2 wC3 = tw[(j + 3 * h) << (9 - sl)];
      if (INV) {
        wA.y = -wA.y; wB0.y = -wB0.y; wB1.y = -wB1.y;
        wC0.y = -wC0.y; wC1.y = -wC1.y; wC2.y = -wC2.y; wC3.y = -wC3.y;
      }
      float2 t;
      t = cmul(wA, a1); float2 b0 = f2a(a0, t), b1 = f2s(a0, t);
      t = cmul(wA, a3); float2 b2 = f2a(a2, t), b3 = f2s(a2, t);
      t = cmul(wA, a5); float2 b4 = f2a(a4, t), b5 = f2s(a4, t);
      t = cmul(wA, a7); float2 b6 = f2a(a6, t), b7 = f2s(a6, t);
      t = cmul(wB0, b2); float2 c0 = f2a(b0, t), c2 = f2s(b0, t);
      t = cmul(wB1, b3); float2 c1 = f2a(b1, t), c3 = f2s(b1, t);
      t = cmul(wB0, b6); float2 c4 = f2a(b4, t), c6 = f2s(b4, t);
      t = cmul(wB1, b7); float2 c5 = f2a(b5, t), c7 = f2s(b5, t);
      t = cmul(wC0, c4); z[zp(i0)]         = f2a(c0, t); z[zp(i0 + 4 * h)] = f2s(c0, t);
      t = cmul(wC1, c5); z[zp(i0 + h)]     = f2a(c1, t); z[zp(i0 + 5 * h)] = f2s(c1, t);
      t = cmul(wC2, c6); z[zp(i0 + 2 * h)] = f2a(c2, t); z[zp(i0 + 6 * h)] = f2s(c2, t);
      t = cmul(wC3, c7); z[zp(i0 + 3 * h)] = f2a(c3, t); z[zp(i0 + 7 * h)] = f2s(c3, t);
    }
    __syncthreads();
  }
  for (int q = tid; q < 512; q += 256) {  // final radix-4 round: stages (10,11)
    float2 a0 = z[zp(q)], a1 = z[zp(q + 512)], a2 = z[zp(q + 1024)], a3 = z[zp(q + 1536)];
    float2 w1 = tw[q << 1], w2 = tw[q], w3 = tw[q + 512];
    if (INV) { w1.y = -w1.y; w2.y = -w2.y; w3.y = -w3.y; }
    float2 t;
    t = cmul(w1, a1); float2 b0 = f2a(a0, t), b1 = f2s(a0, t);
    t = cmul(w1, a3); float2 b2 = f2a(a2, t), b3 = f2s(a2, t);
    t = cmul(w2, b2); z[zp(q)]        = f2a(b0, t); z[zp(q + 1024)] = f2s(b0, t);
    t = cmul(w3, b3); z[zp(q + 512)]  = f2a(b1, t); z[zp(q + 1536)] = f2s(b1, t);
  }
  __syncthreads();
}

// ---------------- init kernels ----------------
__global__ void k_twiddle(float2* tw) {
  int i = blockIdx.x * 256 + threadIdx.x;
  if (i < 1024) {
    float ang = -6.2831853071795864769f * (float)i / 2048.0f;
    tw[i] = mkf2(cosf(ang), sinf(ang));
  }
}

// rfft of phi columns (pairs packed into one complex FFT)
__global__ void k_fft_phi(const float* __restrict__ phi, float2* __restrict__ Vf,
                          const float2* __restrict__ tw) {
  __shared__ float2 z[2112];
  int tid = threadIdx.x;
  int k0 = blockIdx.x * 2;
  for (int t = tid; t < 1024; t += 256)
    z[zp(t)] = *(const float2*)(phi + (size_t)t * 16 + k0);
  for (int t = 1024 + tid; t < 2048; t += 256) z[zp(t)] = mkf2(0.f, 0.f);
  __syncthreads();
  fft2048<false>(z, tw, tid);
  for (int f = tid; f <= 1024; f += 256) {
    float2 zf = z[zp(f)], zc = z[zp((2048 - f) & 2047)];
    Vf[(size_t)k0 * 1025 + f]       = mkf2(0.5f * (zf.x + zc.x), 0.5f * (zf.y - zc.y));
    Vf[(size_t)(k0 + 1) * 1025 + f] = mkf2(0.5f * (zf.y + zc.y), 0.5f * (zc.x - zf.x));
  }
}

// cpcm[kb][f]: f=1..1023 standard complex scale; slot 0 packs (c_DC, c_Nyq) (both REAL).
__global__ void k_cpcm(const float2* __restrict__ Vf, const float* __restrict__ sigma,
                       float2* __restrict__ cpcm) {
  int idx = blockIdx.x * 256 + threadIdx.x;
  if (idx >= 32 * CPS) return;
  int kb = idx / CPS, f = idx - kb * CPS;
  int k = kb & 15;
  float s = powf(sigma[k], 0.25f) * (1.0f / 2048.0f);
  float2 v = mkf2(0.f, 0.f);
  if (f == 0) {
    float dc = Vf[(size_t)k * 1025].x;          // real
    float ny = Vf[(size_t)k * 1025 + 1024].x;   // real
    v = (kb < 16) ? mkf2(s * dc, s * ny) : mkf2(s * ny, s * dc);
  } else if (f <= 1023) {
    if (kb < 16) {
      v = Vf[(size_t)k * 1025 + f];
    } else {
      float2 t = Vf[(size_t)k * 1025 + (1024 - f)];
      v = mkf2(t.x, -t.y);
    }
    v.x *= s; v.y *= s;
  }
  cpcm[idx] = v;
}

// ---------------- merged: forward FFT (blocks 0..511) + weight cast (blocks 512..4287) --------
// Same-layer merge: both only depend on prior-layer outputs; both complete before gemm0.
// Cast blocks stream HBM while FFT blocks grind LDS -> co-resident overlap at ~8 blocks/CU.
__global__ __launch_bounds__(256)
void k_fwdcast(const f16* __restrict__ hb2, f16* __restrict__ Xbf,
               const float2* __restrict__ tw,
               const float* __restrict__ mp, const float* __restrict__ mm,
               const float* __restrict__ mu, const float* __restrict__ fc1,
               const float* __restrict__ fc2,
               f16* __restrict__ Wsp, f16* __restrict__ Wu,
               f16* __restrict__ Wf1, f16* __restrict__ Wf2) {
  __shared__ __align__(16) char smem[16896];
  int wg = (int)blockIdx.x, tid = threadIdx.x;
  if (wg < 512) {
    // ---- forward FFT of hb2 -> Xbf; rows 0,1 = (DC.re, Nyq.re), rows 2f,2f+1 f=1..1023
    float2* z = (float2*)smem;
    int b = wg >> 8;
    int d0 = (wg & 255) * 2;
    for (int t = tid; t < 1024; t += 256) {
      union { unsigned v; f16 q[2]; } w;
      w.v = *(const unsigned*)(hb2 + (size_t)(b * 1026 + 2 + t) * 512 + d0);
      z[zp(t)] = mkf2((float)w.q[0], (float)w.q[1]);
    }
    for (int t = 1024 + tid; t < 2048; t += 256) z[zp(t)] = mkf2(0.f, 0.f);
    __syncthreads();
    fft2048<false>(z, tw, tid);
    for (int f = tid; f <= 1024; f += 256) {
      float2 zf = z[zp(f)], zc = z[zp((2048 - f) & 2047)];
      float x0r = 0.5f * (zf.x + zc.x), x0i = 0.5f * (zf.y - zc.y);
      float x1r = 0.5f * (zf.y + zc.y), x1i = 0.5f * (zc.x - zf.x);
      union { f16 h2[2]; unsigned u; } pr, pi;
      pr.h2[0] = (f16)x0r; pr.h2[1] = (f16)x1r;
      pi.h2[0] = (f16)x0i; pi.h2[1] = (f16)x1i;
      if (f == 0) {
        *(unsigned*)(Xbf + (size_t)(b * RPB) * 512 + d0) = pr.u;         // DC (im=0)
      } else if (f == 1024) {
        *(unsigned*)(Xbf + (size_t)(b * RPB + 1) * 512 + d0) = pr.u;     // Nyquist (im=0)
      } else {
        *(unsigned*)(Xbf + (size_t)(b * RPB + 2 * f) * 512 + d0)     = pr.u;
        *(unsigned*)(Xbf + (size_t)(b * RPB + 2 * f + 1) * 512 + d0) = pi.u;
      }
    }
    return;
  }
  // ---- weight cast/transpose (identical math to prior k_cast), T[64][65] in smem
  float* T = (float*)smem;
  int blk = wg - 512;
  if (blk < 2048) {                    // Wsp: Wsp[(kb*512+o)][d] = m?[k][d][o]
    int mat = blk >> 6, tile = blk & 63;
    int d0 = (tile >> 3) * 64, o0 = (tile & 7) * 64;
    const float* src = (mat < 16) ? (mp + (size_t)mat * 262144)
                                  : (mm + (size_t)(mat - 16) * 262144);
    for (int q = tid; q < 4096; q += 256) {
      int i = q >> 6, j = q & 63;
      T[i * 65 + j] = src[(size_t)(d0 + i) * 512 + o0 + j];
    }
    __syncthreads();
    for (int q = tid; q < 4096; q += 256) {
      int i = q >> 6, j = q & 63;
      Wsp[(size_t)(mat * 512 + o0 + i) * 512 + d0 + j] = (f16)T[j * 65 + i];
    }
  } else if (blk < 2240) {             // Wu: Wu[o][ip*512+d] = mu[2-ip][d][o]
    int q0 = blk - 2048;
    int ip = q0 >> 6, tile = q0 & 63;
    int d0 = (tile >> 3) * 64, o0 = (tile & 7) * 64;
    const float* src = mu + (size_t)(2 - ip) * 262144;
    for (int q = tid; q < 4096; q += 256) {
      int i = q >> 6, j = q & 63;
      T[i * 65 + j] = src[(size_t)(d0 + i) * 512 + o0 + j];
    }
    __syncthreads();
    for (int q = tid; q < 4096; q += 256) {
      int i = q >> 6, j = q & 63;
      Wu[(size_t)(o0 + i) * 1536 + ip * 512 + d0 + j] = (f16)T[j * 65 + i];
    }
  } else if (blk < 3264) {             // fc1 perm copy: row 2h = y-row h, 2h+1 = gate-row h
    int q0 = blk - 2240;
    size_t e = ((size_t)q0 * 256 + tid) * 8;
    int jj = (int)(e >> 9), col = (int)(e & 511);
    int srow = (jj & 1) ? (2048 + (jj >> 1)) : (jj >> 1);
    const float4* s = (const float4*)(fc1 + (size_t)srow * 512 + col);
    float4 a = s[0], b = s[1];
    union { f16 h[8]; uint4 u; } pk;
    pk.h[0] = (f16)a.x; pk.h[1] = (f16)a.y; pk.h[2] = (f16)a.z; pk.h[3] = (f16)a.w;
    pk.h[4] = (f16)b.x; pk.h[5] = (f16)b.y; pk.h[6] = (f16)b.z; pk.h[7] = (f16)b.w;
    *(uint4*)(Wf1 + (size_t)jj * 512 + col) = pk.u;
  } else {                             // fc2 straight copy (already [o][j])
    int q0 = blk - 3264;
    size_t e = ((size_t)q0 * 256 + tid) * 8;
    const float4* s = (const float4*)(fc2 + e);
    float4 a = s[0], b = s[1];
    union { f16 h[8]; uint4 u; } pk;
    pk.h[0] = (f16)a.x; pk.h[1] = (f16)a.y; pk.h[2] = (f16)a.z; pk.h[3] = (f16)a.w;
    pk.h[4] = (f16)b.x; pk.h[5] = (f16)b.y; pk.h[6] = (f16)b.z; pk.h[7] = (f16)b.w;
    *(uint4*)(Wf2 + e) = pk.u;
  }
}

// ---------------- rmsnorm (f16 x in, zero-padded fp16 hb2 out) ----------------
__global__ void k_rmsnorm(const f16* __restrict__ x, const float* __restrict__ w,
                          f16* __restrict__ hb2) {
  int tid = threadIdx.x, l = tid & 63, wv = tid >> 6;
  int r = blockIdx.x * 4 + wv;
  int b = r >> 10, t = r & 1023;
  const f16* xr = x + (size_t)r * 512;
  f16* hr = hb2 + (size_t)(b * 1026 + 2 + t) * 512;
  float v[8]; float ss = 0.f;
#pragma unroll
  for (int j = 0; j < 8; ++j) { v[j] = (float)xr[j * 64 + l]; ss += v[j] * v[j]; }
#pragma unroll
  for (int o = 32; o; o >>= 1) ss += __shfl_xor(ss, o, 64);
  float rn = rsqrtf(ss * (1.f / 512.f) + 1e-5f);
#pragma unroll
  for (int j = 0; j < 8; ++j) {
    float hv = v[j] * rn * w[j * 64 + l];
    hr[j * 64 + l] = (f16)hv;
  }
}

// ---------------- inverse FFT: sum of NPART f16 partials -> spec f16 (512 blocks) ----------------
__global__ void k_fft_inv(const f16* __restrict__ P, f16* __restrict__ spec,
                          const float2* __restrict__ tw) {
  __shared__ float2 z[2112];
  int tid = threadIdx.x;
  int b = blockIdx.x >> 8;
  int o0 = (blockIdx.x & 255) * 2;
  for (int fp = tid; fp < 512; fp += 256) {
    int f0 = fp * 2;
    size_t base0 = (size_t)o0 * RTOT + (size_t)b * RPB + 2 * f0;
    float s0r[2] = {0.f, 0.f}, s0i[2] = {0.f, 0.f};
    float s1r[2] = {0.f, 0.f}, s1i[2] = {0.f, 0.f};
#pragma unroll
    for (int g = 0; g < NPART; ++g) {
      const f16* Pg = P + (size_t)g * 512 * RTOT;
      union { uint2 u; f16 h[4]; } ua, uc;
      ua.u = *(const uint2*)(Pg + base0);
      uc.u = *(const uint2*)(Pg + base0 + RTOT);
      s0r[0] += (float)ua.h[0]; s0i[0] += (float)ua.h[1];
      s0r[1] += (float)ua.h[2]; s0i[1] += (float)ua.h[3];
      s1r[0] += (float)uc.h[0]; s1i[0] += (float)uc.h[1];
      s1r[1] += (float)uc.h[2]; s1i[1] += (float)uc.h[3];
    }
    if (fp == 0) {
      z[zp(0)]    = mkf2(s0r[0], s1r[0]);   // DC of both real o-channels
      z[zp(1024)] = mkf2(s0i[0], s1i[0]);   // Nyquist of both
    } else {
      z[zp(f0)]        = mkf2(s0r[0] - s1i[0], s0i[0] + s1r[0]);
      z[zp(2048 - f0)] = mkf2(s0r[0] + s1i[0], s1r[0] - s0i[0]);
    }
    int f1 = f0 + 1;
    z[zp(f1)]        = mkf2(s0r[1] - s1i[1], s0i[1] + s1r[1]);
    z[zp(2048 - f1)] = mkf2(s0r[1] + s1i[1], s1r[1] - s0i[1]);
  }
  __syncthreads();
  fft2048<true>(z, tw, tid);
  for (int t = tid; t < 1024; t += 256) {
    float2 v = z[zp(t)];
    union { f16 h[2]; unsigned u; } pk;
    pk.h[0] = (f16)v.x; pk.h[1] = (f16)v.y;
    *(unsigned*)(spec + (size_t)(b * 1024 + t) * 512 + o0) = pk.u;
  }
}

// ---------------- unified MFMA GEMM: round-2 structure, 16x16x32 (measured best) ----------
// Flat s-loop, single 32KB LDS buffer, two __syncthreads per step. Do NOT unroll /
// double-buffer / vmcnt / raise occupancy / 32x32 MFMA (r3=135, r4=191, r5=363, r6=167,
// r10 32x32=111 w/ 8.4M bank conflicts — vs this structure's 89-98us at 0 conflicts).
// MODE 0: spectral  A=Xbf  B=Wsp (kb loop, complex-scale; DC/Nyq packed row fix) -> P[g] f16
// MODE 1: AR        A=Wu   B=hb2 window -> x1 = x + spec + acc (f16)
// MODE 2: MLP1      A=fc1p B=x1 -> g1 = y*silu(gate) (f16)
// MODE 3: MLP2      A=fc2  B=g1 -> x = x + x1 + acc (f16)
template<int MODE, int MR, int NR>
__device__ __forceinline__ void stage(const f16* __restrict__ A, const f16* __restrict__ B0,
                                      int r0, int c0, int bz, int tid, int s,
                                      f16* As, f16* Bs) {
  constexpr int LDA = (MODE == 0) ? 512 : (MODE == 1) ? 1536 : (MODE == 2) ? 512 : 2048;
  const int kA = (MODE == 0) ? ((s & 7) * 64) : s * 64;
  const int rowl = tid >> 3;
  const int lc8 = ((tid & 7) ^ (rowl & 7)) * 8;   // swizzled chunk * 8 (f16)
  f16* lA = As + ((tid >> 6) << 9);               // wave-uniform LDS base
  f16* lB = Bs + ((tid >> 6) << 9);
#pragma unroll
  for (int i = 0; i < MR; ++i) {
    int row = i * 32 + rowl;
    gl16(A + (size_t)(r0 + row) * LDA + kA + lc8, lA + i * 2048);
  }
#pragma unroll
  for (int i = 0; i < NR; ++i) {
    int row = i * 32 + rowl;
    const f16* bs;
    if constexpr (MODE == 0) {
      int kb = bz * 8 + (s >> 3);
      bs = B0 + (size_t)(kb * 512 + c0 + row) * 512 + (s & 7) * 64 + lc8;
    } else if constexpr (MODE == 1) {
      int ip = s >> 3, d0 = (s & 7) * 64;
      int rr = c0 + row;
      int b = rr >> 10, t = rr & 1023;
      bs = B0 + (size_t)(b * 1026 + t + ip) * 512 + d0 + lc8;   // pad rows are zero
    } else {
      constexpr int LDB = (MODE == 2) ? 512 : 2048;
      bs = B0 + (size_t)(c0 + row) * LDB + s * 64 + lc8;
    }
    gl16(bs, lB + i * 2048);
  }
}

template<int MR, int NR>
__device__ __forceinline__ void mma_step(const f16* As, const f16* Bs, int l, int wr, int wc,
                                         f32x4 acc[MR][NR]) {
  const int lr = l & 15, kg = l >> 4, sw = l & 7;
#pragma unroll
  for (int kk = 0; kk < 2; ++kk) {
    half8 af[MR], bf[NR];
    const int pc8 = (((kk * 4 + kg) ^ sw) << 3);
#pragma unroll
    for (int m = 0; m < MR; ++m)
      af[m] = *(const half8*)(As + (wr * (MR * 16) + m * 16 + lr) * 64 + pc8);
#pragma unroll
    for (int n = 0; n < NR; ++n)
      bf[n] = *(const half8*)(Bs + (wc * (NR * 16) + n * 16 + lr) * 64 + pc8);
#pragma unroll
    for (int m = 0; m < MR; ++m)
#pragma unroll
      for (int n = 0; n < NR; ++n)
        acc[m][n] = __builtin_amdgcn_mfma_f32_16x16x32_f16(af[m], bf[n], acc[m][n], 0, 0, 0);
  }
}

template<int MODE, int MR, int NR>
__global__ __launch_bounds__(256, (MODE == 0) ? 2 : ((MODE == 2) ? 3 : 4))
void k_gemm(const f16* __restrict__ A, const f16* __restrict__ B0,
            const float* __restrict__ aux0, const f16* auxA, const f16* auxB,
            f16* __restrict__ outH) {
  __shared__ __align__(16) f16 As[MR * 32 * 64];
  __shared__ __align__(16) f16 Bs[NR * 32 * 64];
  const int tid = threadIdx.x, l = tid & 63, wvi = tid >> 6;
  const int wr = wvi >> 1, wc = wvi & 1;
  int bx, by, bz;
  if constexpr (MODE == 0) {           // 1D grid of 512 = 8 * 64, bijective XCD chunk swizzle
    int wg = (int)blockIdx.x;
    wg = (wg & 7) * 64 + (wg >> 3);
    bz = wg >> 7; int rem = wg & 127;
    by = rem >> 2; bx = rem & 3;
  } else { bx = blockIdx.x; by = blockIdx.y; bz = 0; }
  const int r0 = by * (MR * 32), c0 = bx * (NR * 32);
  constexpr int KS = (MODE == 0) ? 64 : (MODE == 1) ? 24 : (MODE == 2) ? 8 : 32;

  f32x4 acc[MR][NR];
  f32x4 crun[MR][NR];
  f32x4 zz = {0.f, 0.f, 0.f, 0.f};
#pragma unroll
  for (int m = 0; m < MR; ++m)
#pragma unroll
    for (int n = 0; n < NR; ++n) { acc[m][n] = zz; crun[m][n] = zz; }

  for (int s = 0; s < KS; ++s) {
    __syncthreads();                   // prior mma's LDS reads done
    stage<MODE, MR, NR>(A, B0, r0, c0, bz, tid, s, As, Bs);
    __syncthreads();                   // staging landed (compiler drains vmcnt)
    mma_step<MR, NR>(As, Bs, l, wr, wc, acc);
    if constexpr (MODE == 0) {
      if ((s & 7) == 7) {
        int kb = bz * 8 + (s >> 3);
#pragma unroll
        for (int m = 0; m < MR; ++m) {
          int R = r0 + wr * (MR * 16) + m * 16 + ((l >> 4) << 2);
          int rb = R & (RPB - 1);
          bool dc = (rb == 0);         // rows 0,1 = packed (DC.re, Nyq.re): scale separately
          float4 cs = *(const float4*)(aux0 + (size_t)kb * (CPS * 2) + (rb >> 1) * 2);
          float t1 = dc ? 0.f : cs.y;
          float t2 = dc ? cs.y : cs.x;
#pragma unroll
          for (int n = 0; n < NR; ++n) {
            f32x4 p = acc[m][n];
            crun[m][n].x += cs.x * p.x - t1 * p.y;
            crun[m][n].y += t2 * p.y + t1 * p.x;
            crun[m][n].z += cs.z * p.z - cs.w * p.w;
            crun[m][n].w += cs.z * p.w + cs.w * p.z;
            acc[m][n] = zz;
          }
        }
      }
    }
  }

  if constexpr (MODE == 0) {
    f16* P = outH + (size_t)bz * (512ull * RTOT);
#pragma unroll
    for (int m = 0; m < MR; ++m) {
      int R0 = r0 + wr * (MR * 16) + m * 16 + ((l >> 4) << 2);
#pragma unroll
      for (int n = 0; n < NR; ++n) {
        int o = c0 + wc * (NR * 16) + n * 16 + (l & 15);
        union { f16 h[4]; uint2 u; } pk;
        pk.h[0] = (f16)crun[m][n].x; pk.h[1] = (f16)crun[m][n].y;
        pk.h[2] = (f16)crun[m][n].z; pk.h[3] = (f16)crun[m][n].w;
        *(uint2*)(P + (size_t)o * RTOT + R0) = pk.u;
      }
    }
  } else if constexpr (MODE == 1) {
#pragma unroll
    for (int m = 0; m < MR; ++m) {
      int o0 = r0 + wr * (MR * 16) + m * 16 + ((l >> 4) << 2);
#pragma unroll
      for (int n = 0; n < NR; ++n) {
        int r = c0 + wc * (NR * 16) + n * 16 + (l & 15);
        union { uint2 u; f16 h[4]; } xv, sv;
        xv.u = *(const uint2*)(auxA + (size_t)r * 512 + o0);
        sv.u = *(const uint2*)(auxB + (size_t)r * 512 + o0);
        f32x4 a = acc[m][n];
        union { f16 h[4]; uint2 u; } pk;
        pk.h[0] = (f16)((float)xv.h[0] + (float)sv.h[0] + a.x);
        pk.h[1] = (f16)((float)xv.h[1] + (float)sv.h[1] + a.y);
        pk.h[2] = (f16)((float)xv.h[2] + (float)sv.h[2] + a.z);
        pk.h[3] = (f16)((float)xv.h[3] + (float)sv.h[3] + a.w);
        *(uint2*)(outH + (size_t)r * 512 + o0) = pk.u;
      }
    }
  } else if constexpr (MODE == 2) {
#pragma unroll
    for (int m = 0; m < MR; ++m) {
      int jj0 = r0 + wr * (MR * 16) + m * 16 + ((l >> 4) << 2);
      int h2 = jj0 >> 1;
#pragma unroll
      for (int n = 0; n < NR; ++n) {
        int r = c0 + wc * (NR * 16) + n * 16 + (l & 15);
        f32x4 a = acc[m][n];
        float v0 = a.x * (a.y / (1.f + __expf(-a.y)));
        float v1 = a.z * (a.w / (1.f + __expf(-a.w)));
        union { f16 h[2]; unsigned u; } pk;
        pk.h[0] = (f16)v0; pk.h[1] = (f16)v1;
        *(unsigned*)(outH + (size_t)r * 2048 + h2) = pk.u;
      }
    }
  } else {
#pragma unroll
    for (int m = 0; m < MR; ++m) {
      int o0 = r0 + wr * (MR * 16) + m * 16 + ((l >> 4) << 2);
#pragma unroll
      for (int n = 0; n < NR; ++n) {
        int r = c0 + wc * (NR * 16) + n * 16 + (l & 15);
        union { uint2 u; f16 h[4]; } xv, x1v;
        xv.u  = *(const uint2*)(auxA + (size_t)r * 512 + o0);
        x1v.u = *(const uint2*)(auxB + (size_t)r * 512 + o0);
        f32x4 a = acc[m][n];
        union { f16 h[4]; uint2 u; } pk;
        pk.h[0] = (f16)((float)xv.h[0] + (float)x1v.h[0] + a.x);
        pk.h[1] = (f16)((float)xv.h[1] + (float)x1v.h[1] + a.y);
        pk.h[2] = (f16)((float)xv.h[2] + (float)x1v.h[2] + a.z);
        pk.h[3] = (f16)((float)xv.h[3] + (float)x1v.h[3] + a.w);
        *(uint2*)(outH + (size_t)r * 512 + o0) = pk.u;
      }
    }
  }
}

// ---------------- small projections ----------------
__global__ void k_inproj(const float* __restrict__ inp, const float* __restrict__ W,
                         f16* __restrict__ x) {
  __shared__ float row[64];
  int r = blockIdx.x, tid = threadIdx.x;
  if (tid < 64) row[tid] = inp[(size_t)r * 64 + tid];
  __syncthreads();
  for (int o = tid; o < 512; o += 256) {
    const float* wr = W + (size_t)o * 64;
    float acc = 0.f;
#pragma unroll 8
    for (int q = 0; q < 64; ++q) acc += row[q] * wr[q];
    x[(size_t)r * 512 + o] = (f16)acc;
  }
}

__global__ void k_outproj(const f16* __restrict__ x, const float* __restrict__ W,
                          float* out, int add) {
  __shared__ float row[512];
  int r = blockIdx.x, tid = threadIdx.x;
  for (int i = tid; i < 512; i += 256) row[i] = (float)x[(size_t)r * 512 + i];
  __syncthreads();
  int o = tid >> 2, part = tid & 3;
  const float* wr = W + (size_t)o * 512 + part * 128;
  const float* rp = row + part * 128;
  float acc = 0.f;
#pragma unroll 16
  for (int q = 0; q < 128; ++q) acc += rp[q] * wr[q];
  acc += __shfl_xor(acc, 1, 64);
  acc += __shfl_xor(acc, 2, 64);
  if (part == 0) {
    if (add) out[(size_t)r * 64 + o] += acc;
    else     out[(size_t)r * 64 + o] = acc;
  }
}

// ---------------- host ----------------
extern "C" void kernel_launch(void* const* d_in, const int* in_sizes, int n_in,
                              void* d_out, int out_size, void* d_ws, size_t ws_size,
                              hipStream_t stream) {
  const float* inputs    = (const float*)d_in[0];
  const float* sigma     = (const float*)d_in[1];
  const float* phi       = (const float*)d_in[2];
  const float* in_proj_w = (const float*)d_in[3];
  const float* rn_w      = (const float*)d_in[4];
  const float* M_u       = (const float*)d_in[5];
  const float* M_phi_p   = (const float*)d_in[6];
  const float* M_phi_m   = (const float*)d_in[7];
  const float* fc1       = (const float*)d_in[8];
  const float* fc2       = (const float*)d_in[9];
  const float* out_proj_w= (const float*)d_in[10];
  float* out = (float*)d_out;

  char* ws = (char*)d_ws;
  size_t off = 0;
  auto alloc = [&](size_t bytes) -> void* {
    void* p = ws + off;
    off += (bytes + 255) & ~(size_t)255;
    return p;
  };
  float2* tw   = (float2*)alloc(1024 * 8);
  float2* Vf   = (float2*)alloc((size_t)16 * 1025 * 8);
  float2* cpcm = (float2*)alloc((size_t)32 * CPS * 8);
  f16*    x    = (f16*)alloc((size_t)NROW * 512 * 2);
  f16*    hb2  = (f16*)alloc((size_t)2052 * 512 * 2);   // 2 batches x (2 pad + 1024) rows
  f16*    x1   = (f16*)alloc((size_t)NROW * 512 * 2);
  f16*    spec = (f16*)alloc((size_t)NROW * 512 * 2);
  f16*    Xbf  = (f16*)alloc((size_t)RTOT * 512 * 2);
  f16*    P    = (f16*)alloc((size_t)NPART * 512 * RTOT * 2);
  f16*    g1   = (f16*)alloc((size_t)NROW * 2048 * 2);
  f16*    Wsp  = (f16*)alloc((size_t)16384 * 512 * 2);
  f16*    Wu   = (f16*)alloc((size_t)512 * 1536 * 2);
  f16*    Wf1  = (f16*)alloc((size_t)4096 * 512 * 2);
  f16*    Wf2  = (f16*)alloc((size_t)512 * 2048 * 2);
  if (off > ws_size) return;  // workspace too small: fail loudly (output stays poisoned)

  // zero the AR window pad rows (rows 0,1 of each batch block in hb2)
  hipMemsetAsync(hb2, 0, 2 * 512 * sizeof(f16), stream);
  hipMemsetAsync(hb2 + (size_t)1026 * 512, 0, 2 * 512 * sizeof(f16), stream);
  k_twiddle<<<4, 256, 0, stream>>>(tw);
  k_fft_phi<<<8, 256, 0, stream>>>(phi, Vf, tw);
  k_cpcm<<<133, 256, 0, stream>>>(Vf, sigma, cpcm);

  for (int m = 0; m < 2; ++m) {
    k_inproj<<<NROW, 256, 0, stream>>>(inputs, in_proj_w + (size_t)m * 512 * 64, x);
    for (int li = 0; li < 2; ++li) {
      int ml = m * 2 + li;
      k_rmsnorm<<<512, 256, 0, stream>>>(x, rn_w + (size_t)ml * 512, hb2);
      k_fwdcast<<<512 + 3776, 256, 0, stream>>>(
          hb2, Xbf, tw,
          M_phi_p + (size_t)ml * 16 * 262144, M_phi_m + (size_t)ml * 16 * 262144,
          M_u + (size_t)ml * 3 * 262144, fc1 + (size_t)ml * 4096 * 512,
          fc2 + (size_t)ml * 512 * 2048, Wsp, Wu, Wf1, Wf2);
      k_gemm<0, 4, 4><<<dim3(512), 256, 0, stream>>>(Xbf, Wsp, (const float*)cpcm,
                                                     nullptr, nullptr, P);
      k_fft_inv<<<512, 256, 0, stream>>>(P, spec, tw);
      k_gemm<1, 2, 2><<<dim3(32, 8), 256, 0, stream>>>(Wu, hb2, nullptr, x, spec, x1);
      k_gemm<2, 4, 4><<<dim3(16, 32), 256, 0, stream>>>(Wf1, x1, nullptr,
                                                        nullptr, nullptr, g1);
      k_gemm<3, 2, 2><<<dim3(32, 8), 256, 0, stream>>>(Wf2, g1, nullptr, x, x1, x);
    }
    k_outproj<<<NROW, 256, 0, stream>>>(x, out_proj_w + (size_t)m * 64 * 512, out, m);
  }
}